// Round 6
// baseline (207.289 us; speedup 1.0000x reference)
//
#include <hip/hip_runtime.h>
#include <math.h>

#define BATCH 16
#define SEQLEN 4096
#define D_MODEL 96
#define D_STATE 6
#define D_CONV 9
#define D_INNER 192
#define DT_RANK 6
#define NPOS (BATCH * SEQLEN)

#define NC2 128            // chunks per sequence
#define CT2 (SEQLEN / NC2) // 32 steps per chunk
#define CPB 2              // chunks per block (ILP-2 scan)
#define NSEG 16            // level-2 segments
#define CPS (NC2 / NSEG)   // chunks per segment = 8

// workspace layout (in floats). xs/z stored as bf16 (ushort). z is PRE-SILU'd.
#define OFF_XS    0L
#define OFF_Z     (OFF_XS   + (long)NPOS * 96)
#define OFF_OUT4  (OFF_Z    + (long)NPOS * 96)       // B*NC2*5*192 float4s
#define OFF_SEG   (OFF_OUT4 + (long)BATCH * NC2 * 5 * 192 * 4)
#define OFF_XPART (OFF_SEG  + (long)BATCH * NSEG * 5 * 192 * 4)  // 2048*96 xbar partials
#define OFF_XPB   (OFF_XPART + (long)(NPOS / 32) * 96)           // 18x192 bf16 x_proj_w
#define OFF_WB16  (OFF_XPB  + 18 * 96)                           // 384x96 bf16 in_proj_w

typedef short v8s __attribute__((ext_vector_type(8)));   // 8 x bf16 (MFMA A/B frag)
typedef float v4f __attribute__((ext_vector_type(4)));   // MFMA C/D frag

// fast transcendentals — abs threshold 2e-2, ample headroom
__device__ __forceinline__ float silu_fast(float v) {
    return __fdividef(v, 1.0f + __expf(-v));
}
__device__ __forceinline__ float softplus_fast(float v) {
    return (v > 20.0f) ? v : __logf(1.0f + __expf(v));
}
__device__ __forceinline__ float eluf(float v) {
    return (v > 0.0f) ? v : expm1f(v);
}
__device__ __forceinline__ unsigned int pack_bf16(float a, float b) {
    unsigned int ua = __float_as_uint(a), ub = __float_as_uint(b);
    ua += 0x7FFFu + ((ua >> 16) & 1u);
    ub += 0x7FFFu + ((ub >> 16) & 1u);
    return (ua >> 16) | (ub & 0xFFFF0000u);
}
__device__ __forceinline__ unsigned short bf16h(float v) {
    unsigned int u = __float_as_uint(v);
    u += 0x7FFFu + ((u >> 16) & 1u);
    return (unsigned short)(u >> 16);
}
__device__ __forceinline__ float bf2f(unsigned short h) {
    return __uint_as_float(((unsigned int)h) << 16);
}

// ---------------------------------------------------------------------------
// K0: one-time weight packs (f32 -> bf16): in_proj_w (384x96) and
// x_proj_w (18x192).
// ---------------------------------------------------------------------------
#define K0_W (384 * 48)
#define K0_X (18 * 96)
__global__ __launch_bounds__(256) void k0_pack(
    const float* __restrict__ W, const float* __restrict__ x_proj_w,
    unsigned int* __restrict__ wb16, unsigned int* __restrict__ xpb)
{
    int i = blockIdx.x * 256 + threadIdx.x;
    if (i < K0_W) {
        const float2 wv = *(const float2*)&W[2 * i];
        wb16[i] = pack_bf16(wv.x, wv.y);
    } else if (i < K0_W + K0_X) {
        int j = i - K0_W;
        const float2 wv = *(const float2*)&x_proj_w[2 * j];
        xpb[j] = pack_bf16(wv.x, wv.y);
    }
}

// ---------------------------------------------------------------------------
// K1 (MFMA): RMSNorm (fp32) + in_proj via bf16 mfma_f32_16x16x32.
// Round-19 form (measured 41.7 us) — unchanged.
// ---------------------------------------------------------------------------
#define TP1 32
__global__ __launch_bounds__(256, 4) void k1_rmsnorm_inproj(
    const float* __restrict__ x, const unsigned short* __restrict__ wb16,
    const float* __restrict__ norm_w,
    unsigned short* __restrict__ xs, unsigned short* __restrict__ z,
    float* __restrict__ xpart)
{
    __shared__ float hRow[TP1 * 100];        // 12.8 KB [p][d] stride 100
    __shared__ unsigned int s_hA[TP1 * 52];  // 6.7 KB bf16 pairs [pos][dpair]
    __shared__ float s_part[TP1][8];         // 1 KB rms partials
    __shared__ float s_scale[TP1];           // 128 B

    const int tid = threadIdx.x;
    const long p0 = (long)blockIdx.x * TP1;

    // stage x as float4 (16B/lane coalesced; aligned b128 LDS stores)
    {
        const float4* x4 = (const float4*)&x[p0 * 96];
        for (int i = tid; i < TP1 * 24; i += 256) {
            int p = i / 24, dq = i - p * 24;
            *(float4*)&hRow[p * 100 + dq * 4] = x4[i];
        }
    }
    __syncthreads();

    // rms partials: thread (p, g) sums d = g, g+8, ... (12 terms)
    {
        int p = tid >> 3, g = tid & 7;
        float ss = 0.0f;
        for (int d = g; d < 96; d += 8) { float v = hRow[p * 100 + d]; ss += v * v; }
        s_part[p][g] = ss;
    }
    __syncthreads();

    if (tid < TP1) {
        float ss = 0.0f;
#pragma unroll
        for (int g = 0; g < 8; g++) ss += s_part[tid][g];
        s_scale[tid] = 1.0f / sqrtf(ss / 96.0f + 1e-5f);
    } else if (tid < TP1 + 96) {
        // xbar partial for this 32-pos tile (plain store — no atomics)
        int d = tid - TP1;
        float s = 0.0f;
        for (int p = 0; p < TP1; p++) s += hRow[p * 100 + d];
        xpart[(long)blockIdx.x * 96 + d] = s;
    }
    __syncthreads();

    {
        const float2* nw2 = (const float2*)norm_w;
        for (int i = tid; i < TP1 * 48; i += 256) {
            int p = i / 48, dp = i - p * 48;
            float sc = s_scale[p];
            float2 nv = nw2[dp];
            float v0 = hRow[p * 100 + 2 * dp]     * sc * nv.x;
            float v1 = hRow[p * 100 + 2 * dp + 1] * sc * nv.y;
            s_hA[p * 52 + dp] = pack_bf16(v0, v1);
        }
    }
    __syncthreads();   // hA complete

    const int wave = tid >> 6, lane = tid & 63;
    const int quad = lane >> 4, ln = lane & 15;
    const int n0 = wave * 96;

    // acc[mt][nt] = D[j-tile nt][pos-tile mt] (operand-swapped mfma(W,h))
    v4f acc[2][6];
#pragma unroll
    for (int mt = 0; mt < 2; mt++)
#pragma unroll
        for (int nt = 0; nt < 6; nt++) acc[mt][nt] = (v4f){0.f, 0.f, 0.f, 0.f};

    for (int kc = 0; kc < 3; kc++) {
        v8s bfh[2];
#pragma unroll
        for (int mt = 0; mt < 2; mt++)
            bfh[mt] = *(const v8s*)&s_hA[(mt * 16 + ln) * 52 + kc * 16 + quad * 4];
#pragma unroll
        for (int nt = 0; nt < 6; nt++) {
            // B-frag straight from global bf16 W (L2-hot, 16B aligned)
            v8s aw = *(const v8s*)&wb16[(n0 + nt * 16 + ln) * 96 + kc * 32 + quad * 8];
            acc[0][nt] = __builtin_amdgcn_mfma_f32_16x16x32_bf16(aw, bfh[0], acc[0][nt], 0, 0, 0);
            acc[1][nt] = __builtin_amdgcn_mfma_f32_16x16x32_bf16(aw, bfh[1], acc[1][nt], 0, 0, 0);
        }
    }

    // epilogue: D[j][pos] — lane owns j = quad*4+r (consecutive), pos = ln.
    // z waves (2,3) apply SiLU before the bf16 pack.
    unsigned short* dst = (wave < 2) ? xs : z;
    const bool is_z = (wave >= 2);
    const int jb = (wave & 1) * 96;
#pragma unroll
    for (int mt = 0; mt < 2; mt++) {
        long pos = p0 + mt * 16 + ln;
#pragma unroll
        for (int nt = 0; nt < 6; nt++) {
            float f0 = acc[mt][nt][0], f1 = acc[mt][nt][1];
            float f2 = acc[mt][nt][2], f3 = acc[mt][nt][3];
            if (is_z) {
                f0 = silu_fast(f0); f1 = silu_fast(f1);
                f2 = silu_fast(f2); f3 = silu_fast(f3);
            }
            uint2 v;
            v.x = pack_bf16(f0, f1);
            v.y = pack_bf16(f2, f3);
            *(uint2*)&dst[pos * D_INNER + jb + nt * 16 + quad * 4] = v;
        }
    }
}

// ---------------------------------------------------------------------------
// K2F: fused conv+silu -> xc (bf16 LDS); dbc GEMM via MFMA; chunk scan.
// Round 21: CPB=2 — each block owns TWO ADJACENT chunks (64 positions).
// Conv runs one rolling window r=0..63 (chunk B's boundary restart is free);
// GEMM does 4 M-tiles (both working waves now do 2 tiles each); the scan
// interleaves two INDEPENDENT chains (A,B) in one loop so chain B's VALU
// fills chain A's LDS/exp latency bubbles (the 36% VALU-idle at 26% occ).
// z packed 2-per-uint (zq[32]) to keep VGPR < ~100 (no big arrays — spill
// lesson from round 17).
// ---------------------------------------------------------------------------
#define SXSTR 200   // ushort stride; 100 dw, %32=4 -> bank spread; 16B-aligned
__global__ __launch_bounds__(192, 4) void k2f_conv_scan(
    const unsigned short* __restrict__ xs, const unsigned short* __restrict__ z,
    const float* __restrict__ conv_w, const float* __restrict__ conv_b,
    const unsigned short* __restrict__ xpb,
    const float* __restrict__ dt_w, const float* __restrict__ dt_b,
    const float* __restrict__ A_log, const float* __restrict__ D_param,
    float4* __restrict__ out4)
{
    __shared__ unsigned short sxc[CPB * CT2 * SXSTR];   // 25.6 KB xc tile [t][e] bf16
    __shared__ float sMeta[CPB * CT2][20];              // 5.12 KB meta rows
    const int e = threadIdx.x;
    const int cidx = blockIdx.x & (NC2 / CPB - 1);      // 64 block-chunks per seq
    const int b = blockIdx.x >> 6;
    const int c0 = cidx * CPB;
    const int l0 = c0 * CT2;                            // 64 positions
    const long brow = (long)b * SEQLEN;

    // conv + silu -> sxc (bf16), one rolling window across both chunks
    float cw[D_CONV];
#pragma unroll
    for (int k = 0; k < D_CONV; k++) cw[k] = conv_w[e * D_CONV + k];
    const float cb = conv_b[e];
    float win[D_CONV];
#pragma unroll
    for (int k = 0; k < 8; k++) {
        int ll = l0 - 8 + k;
        win[k] = (ll >= 0) ? bf2f(xs[(brow + ll) * D_INNER + e]) : 0.0f;
    }
    const unsigned short* xsp = &xs[(brow + l0) * D_INNER + e];
#pragma unroll 8
    for (int r = 0; r < CPB * CT2; r++) {
        win[8] = bf2f(xsp[(long)r * D_INNER]);
        float s = cb;
#pragma unroll
        for (int k = 0; k < D_CONV; k++) s += win[k] * cw[k];
        sxc[r * SXSTR + e] = bf16h(silu_fast(s));
#pragma unroll
        for (int k = 0; k < 8; k++) win[k] = win[k + 1];
    }

    // prefetch z for both chunks, packed 2 bf16 per uint (A in low, B in high)
    const unsigned short* zp = &z[(brow + l0) * D_INNER + e];
    unsigned int zq[CT2];
#pragma unroll
    for (int t = 0; t < CT2; t++) {
        unsigned int lo = zp[(long)t * D_INNER];
        unsigned int hi = zp[(long)(t + CT2) * D_INNER];
        zq[t] = lo | (hi << 16);
    }
    __syncthreads();

    // dbc GEMM via MFMA: D[pos][f] = sum_e xc[pos][e] * xp[f][e]; 4 M-tiles.
    {
        const int wave = e >> 6, lane = e & 63;
        const int quad = lane >> 4, ln = lane & 15;
        if (wave < 2) {
            const int r1 = (ln < 2) ? 16 + ln : 0;   // clamp: f>=18 cols discarded
#pragma unroll
            for (int half = 0; half < 2; half++) {
                const int mt = wave * 2 + half;
                v4f dacc[2];
                dacc[0] = (v4f){0.f, 0.f, 0.f, 0.f};
                dacc[1] = (v4f){0.f, 0.f, 0.f, 0.f};
#pragma unroll
                for (int kc = 0; kc < 6; kc++) {
                    v8s af  = *(const v8s*)&sxc[(mt * 16 + ln) * SXSTR + kc * 32 + quad * 8];
                    v8s bf0 = *(const v8s*)&xpb[ln * 192 + kc * 32 + quad * 8];
                    v8s bf1 = *(const v8s*)&xpb[r1 * 192 + kc * 32 + quad * 8];
                    dacc[0] = __builtin_amdgcn_mfma_f32_16x16x32_bf16(af, bf0, dacc[0], 0, 0, 0);
                    dacc[1] = __builtin_amdgcn_mfma_f32_16x16x32_bf16(af, bf1, dacc[1], 0, 0, 0);
                }
#pragma unroll
                for (int nt = 0; nt < 2; nt++) {
                    int f = nt * 16 + ln;
                    if (f < 18) {
                        int col = (f < 6) ? f : f + 2;
#pragma unroll
                        for (int r = 0; r < 4; r++)
                            sMeta[mt * 16 + quad * 4 + r][col] = dacc[nt][r];
                    }
                }
            }
        }
    }
    __syncthreads();

    float a[D_STATE];
#pragma unroll
    for (int n = 0; n < D_STATE; n++) a[n] = -__expf(A_log[e * D_STATE + n]);
    float dtw[DT_RANK];
#pragma unroll
    for (int q = 0; q < DT_RANK; q++) dtw[q] = dt_w[e * DT_RANK + q];
    const float dtb = dt_b[e];
    const float Dv = D_param[e];
    const float a0 = a[0];

    // structure check: a[n] == (n+1)*a0 (true for A_log = log(tile(1..6)))
    bool pok = true;
#pragma unroll
    for (int n = 1; n < D_STATE; n++)
        pok = pok && (fabsf(a[n] - (float)(n + 1) * a0)
                      <= 1e-4f * (float)(n + 1) * fabsf(a0));
    unsigned long long pmask = __ballot(pok);

    if (pmask == 0xFFFFFFFFFFFFFFFFull) {
        // power-chain path, two interleaved independent chains (A = chunk c0,
        // B = chunk c0+1). dA[n] = E^(n+1); P[n] = Pa^(n+1), Pa scalar.
        float SA[D_STATE], GA[D_STATE], SB[D_STATE], GB[D_STATE];
#pragma unroll
        for (int n = 0; n < D_STATE; n++) {
            SA[n] = 0.0f; GA[n] = 0.0f; SB[n] = 0.0f; GB[n] = 0.0f;
        }
        float PaA = 1.0f, PaB = 1.0f, ysA = 0.0f, ysB = 0.0f;
        for (int t = 0; t < CT2; t++) {
            // ---- chain A ----
            {
                const float4* m4 = (const float4*)&sMeta[t][0];
                float4 m0 = m4[0], m1 = m4[1], mB0 = m4[2], mB1 = m4[3], mC = m4[4];
                float Bv[6] = {mB0.x, mB0.y, mB0.z, mB0.w, mB1.x, mB1.y};
                float Cv[6] = {mB1.z, mB1.w, mC.x, mC.y, mC.z, mC.w};
                float dr = dtb + m0.x * dtw[0] + m0.y * dtw[1] + m0.z * dtw[2]
                         + m0.w * dtw[3] + m1.x * dtw[4] + m1.y * dtw[5];
                float dl = softplus_fast(dr);
                float xv = bf2f(sxc[t * SXSTR + e]);
                float zw = __uint_as_float(zq[t] << 16);
                float dx = dl * xv;
                float y = Dv * xv;
                float E = __expf(dl * a0);
                PaA *= E;
                float dA = E;
                float w = zw * PaA;
#pragma unroll
                for (int n = 0; n < D_STATE; n++) {
                    SA[n] = dA * SA[n] + dx * Bv[n];
                    y += SA[n] * Cv[n];
                    GA[n] += w * Cv[n];
                    dA *= E;
                    w *= PaA;
                }
                ysA += zw * y;
            }
            // ---- chain B ----
            {
                const float4* m4 = (const float4*)&sMeta[CT2 + t][0];
                float4 m0 = m4[0], m1 = m4[1], mB0 = m4[2], mB1 = m4[3], mC = m4[4];
                float Bv[6] = {mB0.x, mB0.y, mB0.z, mB0.w, mB1.x, mB1.y};
                float Cv[6] = {mB1.z, mB1.w, mC.x, mC.y, mC.z, mC.w};
                float dr = dtb + m0.x * dtw[0] + m0.y * dtw[1] + m0.z * dtw[2]
                         + m0.w * dtw[3] + m1.x * dtw[4] + m1.y * dtw[5];
                float dl = softplus_fast(dr);
                float xv = bf2f(sxc[(CT2 + t) * SXSTR + e]);
                float zw = __uint_as_float(zq[t] & 0xFFFF0000u);
                float dx = dl * xv;
                float y = Dv * xv;
                float E = __expf(dl * a0);
                PaB *= E;
                float dA = E;
                float w = zw * PaB;
#pragma unroll
                for (int n = 0; n < D_STATE; n++) {
                    SB[n] = dA * SB[n] + dx * Bv[n];
                    y += SB[n] * Cv[n];
                    GB[n] += w * Cv[n];
                    dA *= E;
                    w *= PaB;
                }
                ysB += zw * y;
            }
        }
        // write-out chunk A
        {
            long ob = (long)(b * NC2 + c0) * 5 * 192 + e;
            float Pa = PaA;
            float P1 = Pa, P2 = P1 * Pa, P3 = P2 * Pa, P4 = P3 * Pa, P5 = P4 * Pa, P6 = P5 * Pa;
            float4 q0, q1, q2, q3, q4;
            q0.x=P1; q0.y=P2; q0.z=P3; q0.w=P4;
            q1.x=P5; q1.y=P6; q1.z=SA[0]; q1.w=SA[1];
            q2.x=SA[2]; q2.y=SA[3]; q2.z=SA[4]; q2.w=SA[5];
            q3.x=GA[0]; q3.y=GA[1]; q3.z=GA[2]; q3.w=GA[3];
            q4.x=GA[4]; q4.y=GA[5]; q4.z=ysA; q4.w=0.0f;
            out4[ob          ] = q0;
            out4[ob + 192    ] = q1;
            out4[ob + 2 * 192] = q2;
            out4[ob + 3 * 192] = q3;
            out4[ob + 4 * 192] = q4;
        }
        // write-out chunk B
        {
            long ob = (long)(b * NC2 + c0 + 1) * 5 * 192 + e;
            float Pa = PaB;
            float P1 = Pa, P2 = P1 * Pa, P3 = P2 * Pa, P4 = P3 * Pa, P5 = P4 * Pa, P6 = P5 * Pa;
            float4 q0, q1, q2, q3, q4;
            q0.x=P1; q0.y=P2; q0.z=P3; q0.w=P4;
            q1.x=P5; q1.y=P6; q1.z=SB[0]; q1.w=SB[1];
            q2.x=SB[2]; q2.y=SB[3]; q2.z=SB[4]; q2.w=SB[5];
            q3.x=GB[0]; q3.y=GB[1]; q3.z=GB[2]; q3.w=GB[3];
            q4.x=GB[4]; q4.y=GB[5]; q4.z=ysB; q4.w=0.0f;
            out4[ob          ] = q0;
            out4[ob + 192    ] = q1;
            out4[ob + 2 * 192] = q2;
            out4[ob + 3 * 192] = q3;
            out4[ob + 4 * 192] = q4;
        }
    } else {
        // generic path: the two chunks sequentially
        for (int cc = 0; cc < CPB; cc++) {
            float S[D_STATE], G[D_STATE], P[D_STATE];
#pragma unroll
            for (int n = 0; n < D_STATE; n++) { S[n] = 0.0f; G[n] = 0.0f; P[n] = 1.0f; }
            float ysum0 = 0.0f;
            for (int t = 0; t < CT2; t++) {
                const float4* m4 = (const float4*)&sMeta[cc * CT2 + t][0];
                float4 m0 = m4[0], m1 = m4[1], mB0 = m4[2], mB1 = m4[3], mC = m4[4];
                float Bv[6] = {mB0.x, mB0.y, mB0.z, mB0.w, mB1.x, mB1.y};
                float Cv[6] = {mB1.z, mB1.w, mC.x, mC.y, mC.z, mC.w};
                float dr = dtb + m0.x * dtw[0] + m0.y * dtw[1] + m0.z * dtw[2]
                         + m0.w * dtw[3] + m1.x * dtw[4] + m1.y * dtw[5];
                float dl = softplus_fast(dr);
                float xv = bf2f(sxc[(cc * CT2 + t) * SXSTR + e]);
                float zw = (cc == 0) ? __uint_as_float(zq[t] << 16)
                                     : __uint_as_float(zq[t] & 0xFFFF0000u);
                float dx = dl * xv;
                float y = Dv * xv;
#pragma unroll
                for (int n = 0; n < D_STATE; n++) {
                    float dA = __expf(dl * a[n]);
                    S[n] = dA * S[n] + dx * Bv[n];
                    P[n] *= dA;
                    y += S[n] * Cv[n];
                    G[n] += zw * P[n] * Cv[n];
                }
                ysum0 += zw * y;
            }
            long ob = (long)(b * NC2 + c0 + cc) * 5 * 192 + e;
            float4 q0, q1, q2, q3, q4;
            q0.x=P[0]; q0.y=P[1]; q0.z=P[2]; q0.w=P[3];
            q1.x=P[4]; q1.y=P[5]; q1.z=S[0]; q1.w=S[1];
            q2.x=S[2]; q2.y=S[3]; q2.z=S[4]; q2.w=S[5];
            q3.x=G[0]; q3.y=G[1]; q3.z=G[2]; q3.w=G[3];
            q4.x=G[4]; q4.y=G[5]; q4.z=ysum0; q4.w=0.0f;
            out4[ob          ] = q0;
            out4[ob + 192    ] = q1;
            out4[ob + 2 * 192] = q2;
            out4[ob + 3 * 192] = q3;
            out4[ob + 4 * 192] = q4;
        }
    }
}

// ---------------------------------------------------------------------------
// K4S: level-1 fold — compose CPS=8 chunks into one segment.
// ---------------------------------------------------------------------------
__global__ __launch_bounds__(192) void k4_seg(
    const float4* __restrict__ out4, float4* __restrict__ seg4)
{
    const int e = threadIdx.x;
    const int s = blockIdx.x & (NSEG - 1);
    const int b = blockIdx.x >> 4;

    float H[D_STATE], Gq[D_STATE], Pp[D_STATE];
#pragma unroll
    for (int n = 0; n < D_STATE; n++) { H[n] = 0.0f; Gq[n] = 0.0f; Pp[n] = 1.0f; }
    float yb = 0.0f;
#pragma unroll 2
    for (int cc = 0; cc < CPS; cc++) {
        int c = s * CPS + cc;
        long ob = (long)(b * NC2 + c) * 5 * 192 + e;
        float4 q0 = out4[ob];
        float4 q1 = out4[ob + 192];
        float4 q2 = out4[ob + 2 * 192];
        float4 q3 = out4[ob + 3 * 192];
        float4 q4 = out4[ob + 4 * 192];
        float Pv[6] = {q0.x, q0.y, q0.z, q0.w, q1.x, q1.y};
        float Sv[6] = {q1.z, q1.w, q2.x, q2.y, q2.z, q2.w};
        float Gv[6] = {q3.x, q3.y, q3.z, q3.w, q4.x, q4.y};
        float g = 0.0f;
#pragma unroll
        for (int n = 0; n < D_STATE; n++) g += Gv[n] * H[n];
        yb += q4.z + g;
#pragma unroll
        for (int n = 0; n < D_STATE; n++) {
            Gq[n] += Gv[n] * Pp[n];
            H[n] = Pv[n] * H[n] + Sv[n];
            Pp[n] *= Pv[n];
        }
    }
    long sb = (long)(b * NSEG + s) * 5 * 192 + e;
    float4 q0, q1, q2, q3, q4;
    q0.x=Pp[0]; q0.y=Pp[1]; q0.z=Pp[2]; q0.w=Pp[3];
    q1.x=Pp[4]; q1.y=Pp[5]; q1.z=H[0]; q1.w=H[1];
    q2.x=H[2]; q2.y=H[3]; q2.z=H[4]; q2.w=H[5];
    q3.x=Gq[0]; q3.y=Gq[1]; q3.z=Gq[2]; q3.w=Gq[3];
    q4.x=Gq[4]; q4.y=Gq[5]; q4.z=yb; q4.w=0.0f;
    seg4[sb          ] = q0;
    seg4[sb + 192    ] = q1;
    seg4[sb + 2 * 192] = q2;
    seg4[sb + 3 * 192] = q3;
    seg4[sb + 4 * 192] = q4;
}

// ---------------------------------------------------------------------------
// K4H: per-batch block: fold NSEG=16 segments -> ybar; fold 128 xbar
// partials (TP1=32 tiles); then output head.
// ---------------------------------------------------------------------------
__global__ __launch_bounds__(192) void k4_head(
    const float4* __restrict__ seg4, const float* __restrict__ xpart,
    const float* __restrict__ Wout,
    const float* __restrict__ fc_w, const float* __restrict__ fc_b,
    const float* __restrict__ mu_w, const float* __restrict__ mu_b,
    const float* __restrict__ sg_w, const float* __restrict__ sg_b,
    float* __restrict__ out)
{
    __shared__ float ybar[D_INNER];
    __shared__ float sxb[D_MODEL];
    __shared__ float evec[D_MODEL];
    __shared__ float feat_s[64];
    const int e = threadIdx.x;
    const int b = blockIdx.x;

    float H[D_STATE];
#pragma unroll
    for (int n = 0; n < D_STATE; n++) H[n] = 0.0f;
    float yb = 0.0f;
#pragma unroll 4
    for (int s = 0; s < NSEG; s++) {
        long ob = (long)(b * NSEG + s) * 5 * 192 + e;
        float4 q0 = seg4[ob];
        float4 q1 = seg4[ob + 192];
        float4 q2 = seg4[ob + 2 * 192];
        float4 q3 = seg4[ob + 3 * 192];
        float4 q4 = seg4[ob + 4 * 192];
        float Pv[6] = {q0.x, q0.y, q0.z, q0.w, q1.x, q1.y};
        float Sv[6] = {q1.z, q1.w, q2.x, q2.y, q2.z, q2.w};
        float Gv[6] = {q3.x, q3.y, q3.z, q3.w, q4.x, q4.y};
        float g = 0.0f;
#pragma unroll
        for (int n = 0; n < D_STATE; n++) g += Gv[n] * H[n];
        yb += q4.z + g;
#pragma unroll
        for (int n = 0; n < D_STATE; n++) H[n] = Pv[n] * H[n] + Sv[n];
    }
    ybar[e] = yb;

    // fold the 128 per-tile xbar partials for this batch (TP1=32)
    if (e < D_MODEL) {
        const float* xp = &xpart[(long)b * 128 * 96 + e];
        float s = 0.0f;
        for (int t = 0; t < 128; t++) s += xp[t * 96];
        sxb[e] = s;
    }
    __syncthreads();

    if (e < D_MODEL) {
        float s = sxb[e];
        const float* wrow = &Wout[e * D_INNER];
        for (int e2 = 0; e2 < D_INNER; e2++) s += ybar[e2] * wrow[e2];
        evec[e] = s / (float)SEQLEN;
    }
    __syncthreads();

    if (e < 64) {
        float s = fc_b[e];
        const float* wrow = &fc_w[e * D_MODEL];
        for (int d = 0; d < D_MODEL; d++) s += evec[d] * wrow[d];
        float f = eluf(tanhf(s));
        feat_s[e] = f;
        out[b * 64 + e] = f; // feat
    }
    __syncthreads();

    if (e < 64) {
        float smu = mu_b[e], ssg = sg_b[e];
        const float* mrow = &mu_w[e * 64];
        const float* srow = &sg_w[e * 64];
        for (int i = 0; i < 64; i++) {
            smu += feat_s[i] * mrow[i];
            ssg += feat_s[i] * srow[i];
        }
        out[1024 + b * 64 + e] = smu;                        // mu
        out[2048 + b * 64 + e] = eluf(ssg) + 1.0f + 1e-14f;  // sigma
    }
}

extern "C" void kernel_launch(void* const* d_in, const int* in_sizes, int n_in,
                              void* d_out, int out_size, void* d_ws, size_t ws_size,
                              hipStream_t stream) {
    const float* x         = (const float*)d_in[0];
    const float* in_proj_w = (const float*)d_in[1];
    const float* conv_w    = (const float*)d_in[2];
    const float* conv_b    = (const float*)d_in[3];
    const float* x_proj_w  = (const float*)d_in[4];
    const float* dt_proj_w = (const float*)d_in[5];
    const float* dt_proj_b = (const float*)d_in[6];
    const float* A_log     = (const float*)d_in[7];
    const float* D_param   = (const float*)d_in[8];
    const float* out_proj_w= (const float*)d_in[9];
    const float* norm_w    = (const float*)d_in[10];
    const float* out_fc_w  = (const float*)d_in[11];
    const float* out_fc_b  = (const float*)d_in[12];
    const float* mu_w      = (const float*)d_in[13];
    const float* mu_b      = (const float*)d_in[14];
    const float* sigma_w   = (const float*)d_in[15];
    const float* sigma_b   = (const float*)d_in[16];
    float* ws = (float*)d_ws;
    float* out = (float*)d_out;

    k0_pack<<<(K0_W + K0_X + 255) / 256, 256, 0, stream>>>(
        in_proj_w, x_proj_w,
        (unsigned int*)(ws + OFF_WB16), (unsigned int*)(ws + OFF_XPB));

    k1_rmsnorm_inproj<<<NPOS / TP1, 256, 0, stream>>>(
        x, (const unsigned short*)(ws + OFF_WB16), norm_w,
        (unsigned short*)(ws + OFF_XS), (unsigned short*)(ws + OFF_Z),
        ws + OFF_XPART);

    k2f_conv_scan<<<BATCH * NC2 / CPB, 192, 0, stream>>>(
        (const unsigned short*)(ws + OFF_XS), (const unsigned short*)(ws + OFF_Z),
        conv_w, conv_b, (const unsigned short*)(ws + OFF_XPB),
        dt_proj_w, dt_proj_b, A_log, D_param,
        (float4*)(ws + OFF_OUT4));

    k4_seg<<<BATCH * NSEG, 192, 0, stream>>>(
        (const float4*)(ws + OFF_OUT4), (float4*)(ws + OFF_SEG));

    k4_head<<<BATCH, 192, 0, stream>>>(
        (const float4*)(ws + OFF_SEG), ws + OFF_XPART, out_proj_w,
        out_fc_w, out_fc_b, mu_w, mu_b, sigma_w, sigma_b, out);
}

// Round 7
// 191.665 us; speedup vs baseline: 1.0815x; 1.0815x over previous
//
#include <hip/hip_runtime.h>
#include <math.h>

#define BATCH 16
#define SEQLEN 4096
#define D_MODEL 96
#define D_STATE 6
#define D_CONV 9
#define D_INNER 192
#define DT_RANK 6
#define NPOS (BATCH * SEQLEN)

#define NC2 128            // chunks per sequence
#define CT2 (SEQLEN / NC2) // 32 steps per chunk
#define HT2 (CT2 / 2)      // 16-step half-chunk (ILP-2 scan)
#define NSEG 16            // level-2 segments
#define CPS (NC2 / NSEG)   // chunks per segment = 8

// workspace layout (in floats). xs/z stored as bf16 (ushort). z is PRE-SILU'd.
#define OFF_XS    0L
#define OFF_Z     (OFF_XS   + (long)NPOS * 96)
#define OFF_OUT4  (OFF_Z    + (long)NPOS * 96)       // B*NC2*5*192 float4s
#define OFF_SEG   (OFF_OUT4 + (long)BATCH * NC2 * 5 * 192 * 4)
#define OFF_XPART (OFF_SEG  + (long)BATCH * NSEG * 5 * 192 * 4)  // 2048*96 xbar partials
#define OFF_XPB   (OFF_XPART + (long)(NPOS / 32) * 96)           // 18x192 bf16 x_proj_w
#define OFF_WB16  (OFF_XPB  + 18 * 96)                           // 384x96 bf16 in_proj_w

typedef short v8s __attribute__((ext_vector_type(8)));   // 8 x bf16 (MFMA A/B frag)
typedef float v4f __attribute__((ext_vector_type(4)));   // MFMA C/D frag

// fast transcendentals — abs threshold 2e-2, ample headroom
__device__ __forceinline__ float silu_fast(float v) {
    return __fdividef(v, 1.0f + __expf(-v));
}
__device__ __forceinline__ float softplus_fast(float v) {
    return (v > 20.0f) ? v : __logf(1.0f + __expf(v));
}
__device__ __forceinline__ float eluf(float v) {
    return (v > 0.0f) ? v : expm1f(v);
}
__device__ __forceinline__ unsigned int pack_bf16(float a, float b) {
    unsigned int ua = __float_as_uint(a), ub = __float_as_uint(b);
    ua += 0x7FFFu + ((ua >> 16) & 1u);
    ub += 0x7FFFu + ((ub >> 16) & 1u);
    return (ua >> 16) | (ub & 0xFFFF0000u);
}
__device__ __forceinline__ unsigned short bf16h(float v) {
    unsigned int u = __float_as_uint(v);
    u += 0x7FFFu + ((u >> 16) & 1u);
    return (unsigned short)(u >> 16);
}
__device__ __forceinline__ float bf2f(unsigned short h) {
    return __uint_as_float(((unsigned int)h) << 16);
}

// ---------------------------------------------------------------------------
// K0: one-time weight packs (f32 -> bf16): in_proj_w (384x96) and
// x_proj_w (18x192).
// ---------------------------------------------------------------------------
#define K0_W (384 * 48)
#define K0_X (18 * 96)
__global__ __launch_bounds__(256) void k0_pack(
    const float* __restrict__ W, const float* __restrict__ x_proj_w,
    unsigned int* __restrict__ wb16, unsigned int* __restrict__ xpb)
{
    int i = blockIdx.x * 256 + threadIdx.x;
    if (i < K0_W) {
        const float2 wv = *(const float2*)&W[2 * i];
        wb16[i] = pack_bf16(wv.x, wv.y);
    } else if (i < K0_W + K0_X) {
        int j = i - K0_W;
        const float2 wv = *(const float2*)&x_proj_w[2 * j];
        xpb[j] = pack_bf16(wv.x, wv.y);
    }
}

// ---------------------------------------------------------------------------
// K1 (MFMA): RMSNorm (fp32) + in_proj via bf16 mfma_f32_16x16x32.
// Round-19 form (measured 41.7 us) — unchanged.
// ---------------------------------------------------------------------------
#define TP1 32
__global__ __launch_bounds__(256, 4) void k1_rmsnorm_inproj(
    const float* __restrict__ x, const unsigned short* __restrict__ wb16,
    const float* __restrict__ norm_w,
    unsigned short* __restrict__ xs, unsigned short* __restrict__ z,
    float* __restrict__ xpart)
{
    __shared__ float hRow[TP1 * 100];        // 12.8 KB [p][d] stride 100
    __shared__ unsigned int s_hA[TP1 * 52];  // 6.7 KB bf16 pairs [pos][dpair]
    __shared__ float s_part[TP1][8];         // 1 KB rms partials
    __shared__ float s_scale[TP1];           // 128 B

    const int tid = threadIdx.x;
    const long p0 = (long)blockIdx.x * TP1;

    // stage x as float4 (16B/lane coalesced; aligned b128 LDS stores)
    {
        const float4* x4 = (const float4*)&x[p0 * 96];
        for (int i = tid; i < TP1 * 24; i += 256) {
            int p = i / 24, dq = i - p * 24;
            *(float4*)&hRow[p * 100 + dq * 4] = x4[i];
        }
    }
    __syncthreads();

    // rms partials: thread (p, g) sums d = g, g+8, ... (12 terms)
    {
        int p = tid >> 3, g = tid & 7;
        float ss = 0.0f;
        for (int d = g; d < 96; d += 8) { float v = hRow[p * 100 + d]; ss += v * v; }
        s_part[p][g] = ss;
    }
    __syncthreads();

    if (tid < TP1) {
        float ss = 0.0f;
#pragma unroll
        for (int g = 0; g < 8; g++) ss += s_part[tid][g];
        s_scale[tid] = 1.0f / sqrtf(ss / 96.0f + 1e-5f);
    } else if (tid < TP1 + 96) {
        // xbar partial for this 32-pos tile (plain store — no atomics)
        int d = tid - TP1;
        float s = 0.0f;
        for (int p = 0; p < TP1; p++) s += hRow[p * 100 + d];
        xpart[(long)blockIdx.x * 96 + d] = s;
    }
    __syncthreads();

    {
        const float2* nw2 = (const float2*)norm_w;
        for (int i = tid; i < TP1 * 48; i += 256) {
            int p = i / 48, dp = i - p * 48;
            float sc = s_scale[p];
            float2 nv = nw2[dp];
            float v0 = hRow[p * 100 + 2 * dp]     * sc * nv.x;
            float v1 = hRow[p * 100 + 2 * dp + 1] * sc * nv.y;
            s_hA[p * 52 + dp] = pack_bf16(v0, v1);
        }
    }
    __syncthreads();   // hA complete

    const int wave = tid >> 6, lane = tid & 63;
    const int quad = lane >> 4, ln = lane & 15;
    const int n0 = wave * 96;

    // acc[mt][nt] = D[j-tile nt][pos-tile mt] (operand-swapped mfma(W,h))
    v4f acc[2][6];
#pragma unroll
    for (int mt = 0; mt < 2; mt++)
#pragma unroll
        for (int nt = 0; nt < 6; nt++) acc[mt][nt] = (v4f){0.f, 0.f, 0.f, 0.f};

    for (int kc = 0; kc < 3; kc++) {
        v8s bfh[2];
#pragma unroll
        for (int mt = 0; mt < 2; mt++)
            bfh[mt] = *(const v8s*)&s_hA[(mt * 16 + ln) * 52 + kc * 16 + quad * 4];
#pragma unroll
        for (int nt = 0; nt < 6; nt++) {
            // B-frag straight from global bf16 W (L2-hot, 16B aligned)
            v8s aw = *(const v8s*)&wb16[(n0 + nt * 16 + ln) * 96 + kc * 32 + quad * 8];
            acc[0][nt] = __builtin_amdgcn_mfma_f32_16x16x32_bf16(aw, bfh[0], acc[0][nt], 0, 0, 0);
            acc[1][nt] = __builtin_amdgcn_mfma_f32_16x16x32_bf16(aw, bfh[1], acc[1][nt], 0, 0, 0);
        }
    }

    // epilogue: D[j][pos] — lane owns j = quad*4+r (consecutive), pos = ln.
    // z waves (2,3) apply SiLU before the bf16 pack.
    unsigned short* dst = (wave < 2) ? xs : z;
    const bool is_z = (wave >= 2);
    const int jb = (wave & 1) * 96;
#pragma unroll
    for (int mt = 0; mt < 2; mt++) {
        long pos = p0 + mt * 16 + ln;
#pragma unroll
        for (int nt = 0; nt < 6; nt++) {
            float f0 = acc[mt][nt][0], f1 = acc[mt][nt][1];
            float f2 = acc[mt][nt][2], f3 = acc[mt][nt][3];
            if (is_z) {
                f0 = silu_fast(f0); f1 = silu_fast(f1);
                f2 = silu_fast(f2); f3 = silu_fast(f3);
            }
            uint2 v;
            v.x = pack_bf16(f0, f1);
            v.y = pack_bf16(f2, f3);
            *(uint2*)&dst[pos * D_INNER + jb + nt * 16 + quad * 4] = v;
        }
    }
}

// ---------------------------------------------------------------------------
// K2F: fused conv+silu -> xc (bf16 LDS); dbc GEMM via MFMA; chunk scan.
// Round 22: ILP-2 scan WITHIN the chunk. Split the 32-step scan into two
// independent 16-step half-chains (B starts from zero state) interleaved in
// one loop — chain B's VALU fills chain A's LDS/exp latency (the 36% idle).
// Analytic combine (same algebra as k4_seg):
//   ysum = ysA + ysB + sum_n GB[n]*SA[n]
//   S[n] = PaB^(n+1)*SA[n] + SB[n];  G[n] = GA[n] + PaA^(n+1)*GB[n]
//   Pa   = PaA*PaB.
// Everything else (LDS 15.4 KB, grid 2048, zv prefetch, unroll-2) is the
// proven 49.7 us round-18 structure. CPB=2's regressions (25.6KB LDS,
// non-unrolled loop -> zq scratch, half grid) are all avoided.
// ---------------------------------------------------------------------------
#define SXSTR 200   // ushort stride; 100 dw, %32=4 -> bank spread; 16B-aligned
__global__ __launch_bounds__(192, 4) void k2f_conv_scan(
    const unsigned short* __restrict__ xs, const unsigned short* __restrict__ z,
    const float* __restrict__ conv_w, const float* __restrict__ conv_b,
    const unsigned short* __restrict__ xpb,
    const float* __restrict__ dt_w, const float* __restrict__ dt_b,
    const float* __restrict__ A_log, const float* __restrict__ D_param,
    float4* __restrict__ out4)
{
    __shared__ unsigned short sxc[CT2 * SXSTR];   // 12.8 KB xc tile [t][e] bf16
    __shared__ float sMeta[CT2][20];              // 2.56 KB: [0:6) dr, [8:14) Bm, [14:20) Cm
    const int e = threadIdx.x;
    const int c = blockIdx.x & (NC2 - 1);
    const int b = blockIdx.x >> 7;
    const int l0 = c * CT2;
    const long brow = (long)b * SEQLEN;

    // conv + silu -> sxc (bf16), fully unrolled rolling window
    float cw[D_CONV];
#pragma unroll
    for (int k = 0; k < D_CONV; k++) cw[k] = conv_w[e * D_CONV + k];
    const float cb = conv_b[e];
    float win[D_CONV];
#pragma unroll
    for (int k = 0; k < 8; k++) {
        int ll = l0 - 8 + k;
        win[k] = (ll >= 0) ? bf2f(xs[(brow + ll) * D_INNER + e]) : 0.0f;
    }
#pragma unroll
    for (int r = 0; r < CT2; r++) {
        win[8] = bf2f(xs[(brow + l0 + r) * D_INNER + e]);
        float s = cb;
#pragma unroll
        for (int k = 0; k < D_CONV; k++) s += win[k] * cw[k];
        sxc[r * SXSTR + e] = bf16h(silu_fast(s));
#pragma unroll
        for (int k = 0; k < 8; k++) win[k] = win[k + 1];
    }

    // prefetch z for the whole chunk (pre-silu'd; independent loads in flight)
    const unsigned short* zp = &z[(brow + l0) * D_INNER + e];
    float zv[CT2];
#pragma unroll
    for (int t = 0; t < CT2; t++) zv[t] = bf2f(zp[(long)t * D_INNER]);
    __syncthreads();

    // dbc GEMM via MFMA: D[pos][f] = sum_e xc[pos][e] * xp[f][e].
    // B fragments load directly from the packed global x_proj_w (L2-hot).
    {
        const int wave = e >> 6, lane = e & 63;
        const int quad = lane >> 4, ln = lane & 15;
        if (wave < 2) {
            const int mt = wave;
            const int r1 = (ln < 2) ? 16 + ln : 0;   // clamp: f>=18 cols discarded
            v4f dacc[2];
            dacc[0] = (v4f){0.f, 0.f, 0.f, 0.f};
            dacc[1] = (v4f){0.f, 0.f, 0.f, 0.f};
#pragma unroll
            for (int kc = 0; kc < 6; kc++) {
                v8s af  = *(const v8s*)&sxc[(mt * 16 + ln) * SXSTR + kc * 32 + quad * 8];
                v8s bf0 = *(const v8s*)&xpb[ln * 192 + kc * 32 + quad * 8];
                v8s bf1 = *(const v8s*)&xpb[r1 * 192 + kc * 32 + quad * 8];
                dacc[0] = __builtin_amdgcn_mfma_f32_16x16x32_bf16(af, bf0, dacc[0], 0, 0, 0);
                dacc[1] = __builtin_amdgcn_mfma_f32_16x16x32_bf16(af, bf1, dacc[1], 0, 0, 0);
            }
#pragma unroll
            for (int nt = 0; nt < 2; nt++) {
                int f = nt * 16 + ln;
                if (f < 18) {
                    int col = (f < 6) ? f : f + 2;
#pragma unroll
                    for (int r = 0; r < 4; r++)
                        sMeta[mt * 16 + quad * 4 + r][col] = dacc[nt][r];
                }
            }
        }
    }
    __syncthreads();

    float a[D_STATE];
#pragma unroll
    for (int n = 0; n < D_STATE; n++) a[n] = -__expf(A_log[e * D_STATE + n]);
    float dtw[DT_RANK];
#pragma unroll
    for (int q = 0; q < DT_RANK; q++) dtw[q] = dt_w[e * DT_RANK + q];
    const float dtb = dt_b[e];
    const float Dv = D_param[e];
    const float a0 = a[0];

    // structure check: a[n] == (n+1)*a0 (true for A_log = log(tile(1..6)))
    bool pok = true;
#pragma unroll
    for (int n = 1; n < D_STATE; n++)
        pok = pok && (fabsf(a[n] - (float)(n + 1) * a0)
                      <= 1e-4f * (float)(n + 1) * fabsf(a0));
    unsigned long long pmask = __ballot(pok);

    if (pmask == 0xFFFFFFFFFFFFFFFFull) {
        // power-chain path, two interleaved half-chunk chains.
        float SA[D_STATE], GA[D_STATE], SB[D_STATE], GB[D_STATE];
#pragma unroll
        for (int n = 0; n < D_STATE; n++) {
            SA[n] = 0.0f; GA[n] = 0.0f; SB[n] = 0.0f; GB[n] = 0.0f;
        }
        float PaA = 1.0f, PaB = 1.0f, ysA = 0.0f, ysB = 0.0f;
#pragma unroll 2
        for (int t = 0; t < HT2; t++) {
            // ---- chain A: steps 0..15 ----
            {
                const float4* m4 = (const float4*)&sMeta[t][0];
                float4 m0 = m4[0], m1 = m4[1], mB0 = m4[2], mB1 = m4[3], mC = m4[4];
                float Bv[6] = {mB0.x, mB0.y, mB0.z, mB0.w, mB1.x, mB1.y};
                float Cv[6] = {mB1.z, mB1.w, mC.x, mC.y, mC.z, mC.w};
                float dr = dtb + m0.x * dtw[0] + m0.y * dtw[1] + m0.z * dtw[2]
                         + m0.w * dtw[3] + m1.x * dtw[4] + m1.y * dtw[5];
                float dl = softplus_fast(dr);
                float xv = bf2f(sxc[t * SXSTR + e]);
                float zw = zv[t];
                float dx = dl * xv;
                float y = Dv * xv;
                float E = __expf(dl * a0);
                PaA *= E;
                float dA = E;
                float w = zw * PaA;
#pragma unroll
                for (int n = 0; n < D_STATE; n++) {
                    SA[n] = dA * SA[n] + dx * Bv[n];
                    y += SA[n] * Cv[n];
                    GA[n] += w * Cv[n];
                    dA *= E;
                    w *= PaA;
                }
                ysA += zw * y;
            }
            // ---- chain B: steps 16..31 (zero-state local scan) ----
            {
                const float4* m4 = (const float4*)&sMeta[HT2 + t][0];
                float4 m0 = m4[0], m1 = m4[1], mB0 = m4[2], mB1 = m4[3], mC = m4[4];
                float Bv[6] = {mB0.x, mB0.y, mB0.z, mB0.w, mB1.x, mB1.y};
                float Cv[6] = {mB1.z, mB1.w, mC.x, mC.y, mC.z, mC.w};
                float dr = dtb + m0.x * dtw[0] + m0.y * dtw[1] + m0.z * dtw[2]
                         + m0.w * dtw[3] + m1.x * dtw[4] + m1.y * dtw[5];
                float dl = softplus_fast(dr);
                float xv = bf2f(sxc[(HT2 + t) * SXSTR + e]);
                float zw = zv[HT2 + t];
                float dx = dl * xv;
                float y = Dv * xv;
                float E = __expf(dl * a0);
                PaB *= E;
                float dA = E;
                float w = zw * PaB;
#pragma unroll
                for (int n = 0; n < D_STATE; n++) {
                    SB[n] = dA * SB[n] + dx * Bv[n];
                    y += SB[n] * Cv[n];
                    GB[n] += w * Cv[n];
                    dA *= E;
                    w *= PaB;
                }
                ysB += zw * y;
            }
        }
        // ---- analytic combine (exact algebra, same as k4_seg fold) ----
        float S[D_STATE], G[D_STATE];
        float ysum0 = ysA + ysB;
        {
            float PAn = 1.0f, PBn = 1.0f;
#pragma unroll
            for (int n = 0; n < D_STATE; n++) {
                PAn *= PaA;                 // PaA^(n+1)
                PBn *= PaB;                 // PaB^(n+1)
                ysum0 += GB[n] * SA[n];
                S[n] = PBn * SA[n] + SB[n];
                G[n] = GA[n] + PAn * GB[n];
            }
        }
        float Pa = PaA * PaB;
        long ob = (long)(b * NC2 + c) * 5 * 192 + e;
        float P1 = Pa, P2 = P1 * Pa, P3 = P2 * Pa, P4 = P3 * Pa, P5 = P4 * Pa, P6 = P5 * Pa;
        float4 q0, q1, q2, q3, q4;
        q0.x=P1; q0.y=P2; q0.z=P3; q0.w=P4;
        q1.x=P5; q1.y=P6; q1.z=S[0]; q1.w=S[1];
        q2.x=S[2]; q2.y=S[3]; q2.z=S[4]; q2.w=S[5];
        q3.x=G[0]; q3.y=G[1]; q3.z=G[2]; q3.w=G[3];
        q4.x=G[4]; q4.y=G[5]; q4.z=ysum0; q4.w=0.0f;
        out4[ob          ] = q0;
        out4[ob + 192    ] = q1;
        out4[ob + 2 * 192] = q2;
        out4[ob + 3 * 192] = q3;
        out4[ob + 4 * 192] = q4;
    } else {
        // generic path
        float S[D_STATE], G[D_STATE], P[D_STATE];
#pragma unroll
        for (int n = 0; n < D_STATE; n++) { S[n] = 0.0f; G[n] = 0.0f; P[n] = 1.0f; }
        float ysum0 = 0.0f;
#pragma unroll 2
        for (int t = 0; t < CT2; t++) {
            const float4* m4 = (const float4*)&sMeta[t][0];
            float4 m0 = m4[0], m1 = m4[1], mB0 = m4[2], mB1 = m4[3], mC = m4[4];
            float Bv[6] = {mB0.x, mB0.y, mB0.z, mB0.w, mB1.x, mB1.y};
            float Cv[6] = {mB1.z, mB1.w, mC.x, mC.y, mC.z, mC.w};
            float dr = dtb + m0.x * dtw[0] + m0.y * dtw[1] + m0.z * dtw[2]
                     + m0.w * dtw[3] + m1.x * dtw[4] + m1.y * dtw[5];
            float dl = softplus_fast(dr);
            float xv = bf2f(sxc[t * SXSTR + e]);
            float zw = zv[t];                 // pre-silu'd
            float dx = dl * xv;
            float y = Dv * xv;
#pragma unroll
            for (int n = 0; n < D_STATE; n++) {
                float dA = __expf(dl * a[n]);
                S[n] = dA * S[n] + dx * Bv[n];
                P[n] *= dA;
                y += S[n] * Cv[n];
                G[n] += zw * P[n] * Cv[n];
            }
            ysum0 += zw * y;
        }
        long ob = (long)(b * NC2 + c) * 5 * 192 + e;
        float4 q0, q1, q2, q3, q4;
        q0.x=P[0]; q0.y=P[1]; q0.z=P[2]; q0.w=P[3];
        q1.x=P[4]; q1.y=P[5]; q1.z=S[0]; q1.w=S[1];
        q2.x=S[2]; q2.y=S[3]; q2.z=S[4]; q2.w=S[5];
        q3.x=G[0]; q3.y=G[1]; q3.z=G[2]; q3.w=G[3];
        q4.x=G[4]; q4.y=G[5]; q4.z=ysum0; q4.w=0.0f;
        out4[ob          ] = q0;
        out4[ob + 192    ] = q1;
        out4[ob + 2 * 192] = q2;
        out4[ob + 3 * 192] = q3;
        out4[ob + 4 * 192] = q4;
    }
}

// ---------------------------------------------------------------------------
// K4S: level-1 fold — compose CPS=8 chunks into one segment.
// ---------------------------------------------------------------------------
__global__ __launch_bounds__(192) void k4_seg(
    const float4* __restrict__ out4, float4* __restrict__ seg4)
{
    const int e = threadIdx.x;
    const int s = blockIdx.x & (NSEG - 1);
    const int b = blockIdx.x >> 4;

    float H[D_STATE], Gq[D_STATE], Pp[D_STATE];
#pragma unroll
    for (int n = 0; n < D_STATE; n++) { H[n] = 0.0f; Gq[n] = 0.0f; Pp[n] = 1.0f; }
    float yb = 0.0f;
#pragma unroll 2
    for (int cc = 0; cc < CPS; cc++) {
        int c = s * CPS + cc;
        long ob = (long)(b * NC2 + c) * 5 * 192 + e;
        float4 q0 = out4[ob];
        float4 q1 = out4[ob + 192];
        float4 q2 = out4[ob + 2 * 192];
        float4 q3 = out4[ob + 3 * 192];
        float4 q4 = out4[ob + 4 * 192];
        float Pv[6] = {q0.x, q0.y, q0.z, q0.w, q1.x, q1.y};
        float Sv[6] = {q1.z, q1.w, q2.x, q2.y, q2.z, q2.w};
        float Gv[6] = {q3.x, q3.y, q3.z, q3.w, q4.x, q4.y};
        float g = 0.0f;
#pragma unroll
        for (int n = 0; n < D_STATE; n++) g += Gv[n] * H[n];
        yb += q4.z + g;
#pragma unroll
        for (int n = 0; n < D_STATE; n++) {
            Gq[n] += Gv[n] * Pp[n];
            H[n] = Pv[n] * H[n] + Sv[n];
            Pp[n] *= Pv[n];
        }
    }
    long sb = (long)(b * NSEG + s) * 5 * 192 + e;
    float4 q0, q1, q2, q3, q4;
    q0.x=Pp[0]; q0.y=Pp[1]; q0.z=Pp[2]; q0.w=Pp[3];
    q1.x=Pp[4]; q1.y=Pp[5]; q1.z=H[0]; q1.w=H[1];
    q2.x=H[2]; q2.y=H[3]; q2.z=H[4]; q2.w=H[5];
    q3.x=Gq[0]; q3.y=Gq[1]; q3.z=Gq[2]; q3.w=Gq[3];
    q4.x=Gq[4]; q4.y=Gq[5]; q4.z=yb; q4.w=0.0f;
    seg4[sb          ] = q0;
    seg4[sb + 192    ] = q1;
    seg4[sb + 2 * 192] = q2;
    seg4[sb + 3 * 192] = q3;
    seg4[sb + 4 * 192] = q4;
}

// ---------------------------------------------------------------------------
// K4H: per-batch block: fold NSEG=16 segments -> ybar; fold 128 xbar
// partials (TP1=32 tiles); then output head.
// ---------------------------------------------------------------------------
__global__ __launch_bounds__(192) void k4_head(
    const float4* __restrict__ seg4, const float* __restrict__ xpart,
    const float* __restrict__ Wout,
    const float* __restrict__ fc_w, const float* __restrict__ fc_b,
    const float* __restrict__ mu_w, const float* __restrict__ mu_b,
    const float* __restrict__ sg_w, const float* __restrict__ sg_b,
    float* __restrict__ out)
{
    __shared__ float ybar[D_INNER];
    __shared__ float sxb[D_MODEL];
    __shared__ float evec[D_MODEL];
    __shared__ float feat_s[64];
    const int e = threadIdx.x;
    const int b = blockIdx.x;

    float H[D_STATE];
#pragma unroll
    for (int n = 0; n < D_STATE; n++) H[n] = 0.0f;
    float yb = 0.0f;
#pragma unroll 4
    for (int s = 0; s < NSEG; s++) {
        long ob = (long)(b * NSEG + s) * 5 * 192 + e;
        float4 q0 = seg4[ob];
        float4 q1 = seg4[ob + 192];
        float4 q2 = seg4[ob + 2 * 192];
        float4 q3 = seg4[ob + 3 * 192];
        float4 q4 = seg4[ob + 4 * 192];
        float Pv[6] = {q0.x, q0.y, q0.z, q0.w, q1.x, q1.y};
        float Sv[6] = {q1.z, q1.w, q2.x, q2.y, q2.z, q2.w};
        float Gv[6] = {q3.x, q3.y, q3.z, q3.w, q4.x, q4.y};
        float g = 0.0f;
#pragma unroll
        for (int n = 0; n < D_STATE; n++) g += Gv[n] * H[n];
        yb += q4.z + g;
#pragma unroll
        for (int n = 0; n < D_STATE; n++) H[n] = Pv[n] * H[n] + Sv[n];
    }
    ybar[e] = yb;

    // fold the 128 per-tile xbar partials for this batch (TP1=32)
    if (e < D_MODEL) {
        const float* xp = &xpart[(long)b * 128 * 96 + e];
        float s = 0.0f;
        for (int t = 0; t < 128; t++) s += xp[t * 96];
        sxb[e] = s;
    }
    __syncthreads();

    if (e < D_MODEL) {
        float s = sxb[e];
        const float* wrow = &Wout[e * D_INNER];
        for (int e2 = 0; e2 < D_INNER; e2++) s += ybar[e2] * wrow[e2];
        evec[e] = s / (float)SEQLEN;
    }
    __syncthreads();

    if (e < 64) {
        float s = fc_b[e];
        const float* wrow = &fc_w[e * D_MODEL];
        for (int d = 0; d < D_MODEL; d++) s += evec[d] * wrow[d];
        float f = eluf(tanhf(s));
        feat_s[e] = f;
        out[b * 64 + e] = f; // feat
    }
    __syncthreads();

    if (e < 64) {
        float smu = mu_b[e], ssg = sg_b[e];
        const float* mrow = &mu_w[e * 64];
        const float* srow = &sg_w[e * 64];
        for (int i = 0; i < 64; i++) {
            smu += feat_s[i] * mrow[i];
            ssg += feat_s[i] * srow[i];
        }
        out[1024 + b * 64 + e] = smu;                        // mu
        out[2048 + b * 64 + e] = eluf(ssg) + 1.0f + 1e-14f;  // sigma
    }
}

extern "C" void kernel_launch(void* const* d_in, const int* in_sizes, int n_in,
                              void* d_out, int out_size, void* d_ws, size_t ws_size,
                              hipStream_t stream) {
    const float* x         = (const float*)d_in[0];
    const float* in_proj_w = (const float*)d_in[1];
    const float* conv_w    = (const float*)d_in[2];
    const float* conv_b    = (const float*)d_in[3];
    const float* x_proj_w  = (const float*)d_in[4];
    const float* dt_proj_w = (const float*)d_in[5];
    const float* dt_proj_b = (const float*)d_in[6];
    const float* A_log     = (const float*)d_in[7];
    const float* D_param   = (const float*)d_in[8];
    const float* out_proj_w= (const float*)d_in[9];
    const float* norm_w    = (const float*)d_in[10];
    const float* out_fc_w  = (const float*)d_in[11];
    const float* out_fc_b  = (const float*)d_in[12];
    const float* mu_w      = (const float*)d_in[13];
    const float* mu_b      = (const float*)d_in[14];
    const float* sigma_w   = (const float*)d_in[15];
    const float* sigma_b   = (const float*)d_in[16];
    float* ws = (float*)d_ws;
    float* out = (float*)d_out;

    k0_pack<<<(K0_W + K0_X + 255) / 256, 256, 0, stream>>>(
        in_proj_w, x_proj_w,
        (unsigned int*)(ws + OFF_WB16), (unsigned int*)(ws + OFF_XPB));

    k1_rmsnorm_inproj<<<NPOS / TP1, 256, 0, stream>>>(
        x, (const unsigned short*)(ws + OFF_WB16), norm_w,
        (unsigned short*)(ws + OFF_XS), (unsigned short*)(ws + OFF_Z),
        ws + OFF_XPART);

    k2f_conv_scan<<<BATCH * NC2, 192, 0, stream>>>(
        (const unsigned short*)(ws + OFF_XS), (const unsigned short*)(ws + OFF_Z),
        conv_w, conv_b, (const unsigned short*)(ws + OFF_XPB),
        dt_proj_w, dt_proj_b, A_log, D_param,
        (float4*)(ws + OFF_OUT4));

    k4_seg<<<BATCH * NSEG, 192, 0, stream>>>(
        (const float4*)(ws + OFF_OUT4), (float4*)(ws + OFF_SEG));

    k4_head<<<BATCH, 192, 0, stream>>>(
        (const float4*)(ws + OFF_SEG), ws + OFF_XPART, out_proj_w,
        out_fc_w, out_fc_b, mu_w, mu_b, sigma_w, sigma_b, out);
}

// Round 8
// 191.452 us; speedup vs baseline: 1.0827x; 1.0011x over previous
//
#include <hip/hip_runtime.h>
#include <math.h>

#define BATCH 16
#define SEQLEN 4096
#define D_MODEL 96
#define D_STATE 6
#define D_CONV 9
#define D_INNER 192
#define DT_RANK 6
#define NPOS (BATCH * SEQLEN)

#define NC2 128            // chunks per sequence
#define CT2 (SEQLEN / NC2) // 32 steps per chunk
#define NSEG 16            // level-2 segments
#define CPS (NC2 / NSEG)   // chunks per segment = 8

// workspace layout (in floats). xs/z stored as bf16 (ushort). z is PRE-SILU'd.
#define OFF_XS    0L
#define OFF_Z     (OFF_XS   + (long)NPOS * 96)
#define OFF_OUT4  (OFF_Z    + (long)NPOS * 96)       // B*NC2*5*192 float4s
#define OFF_SEG   (OFF_OUT4 + (long)BATCH * NC2 * 5 * 192 * 4)
#define OFF_XPART (OFF_SEG  + (long)BATCH * NSEG * 5 * 192 * 4)  // 2048*96 xbar partials
#define OFF_XPB   (OFF_XPART + (long)(NPOS / 32) * 96)           // 18x192 bf16 x_proj_w
#define OFF_WB16  (OFF_XPB  + 18 * 96)                           // 384x96 bf16 in_proj_w

typedef short v8s __attribute__((ext_vector_type(8)));   // 8 x bf16 (MFMA A/B frag)
typedef float v4f __attribute__((ext_vector_type(4)));   // MFMA C/D frag

// fast transcendentals — abs threshold 2e-2, ample headroom
__device__ __forceinline__ float silu_fast(float v) {
    return __fdividef(v, 1.0f + __expf(-v));
}
__device__ __forceinline__ float softplus_fast(float v) {
    return (v > 20.0f) ? v : __logf(1.0f + __expf(v));
}
__device__ __forceinline__ float eluf(float v) {
    return (v > 0.0f) ? v : expm1f(v);
}
__device__ __forceinline__ unsigned int pack_bf16(float a, float b) {
    unsigned int ua = __float_as_uint(a), ub = __float_as_uint(b);
    ua += 0x7FFFu + ((ua >> 16) & 1u);
    ub += 0x7FFFu + ((ub >> 16) & 1u);
    return (ua >> 16) | (ub & 0xFFFF0000u);
}
__device__ __forceinline__ unsigned short bf16h(float v) {
    unsigned int u = __float_as_uint(v);
    u += 0x7FFFu + ((u >> 16) & 1u);
    return (unsigned short)(u >> 16);
}
__device__ __forceinline__ float bf2f(unsigned short h) {
    return __uint_as_float(((unsigned int)h) << 16);
}

// ---------------------------------------------------------------------------
// K0: one-time weight packs (f32 -> bf16): in_proj_w (384x96) and
// x_proj_w (18x192).
// ---------------------------------------------------------------------------
#define K0_W (384 * 48)
#define K0_X (18 * 96)
__global__ __launch_bounds__(256) void k0_pack(
    const float* __restrict__ W, const float* __restrict__ x_proj_w,
    unsigned int* __restrict__ wb16, unsigned int* __restrict__ xpb)
{
    int i = blockIdx.x * 256 + threadIdx.x;
    if (i < K0_W) {
        const float2 wv = *(const float2*)&W[2 * i];
        wb16[i] = pack_bf16(wv.x, wv.y);
    } else if (i < K0_W + K0_X) {
        int j = i - K0_W;
        const float2 wv = *(const float2*)&x_proj_w[2 * j];
        xpb[j] = pack_bf16(wv.x, wv.y);
    }
}

// ---------------------------------------------------------------------------
// K1 (MFMA): RMSNorm + in_proj via bf16 mfma_f32_16x16x32.
// Round 23: register-resident prologue, ONE barrier (was 5).
// Thread (p,g)=(tid>>3,tid&7) holds position p's elements d=g*12..g*12+11
// in registers. RMS via shfl_xor(1,2,4) within the 8 g-lanes; xbar column
// partials via shfl_xor(8,16,32) across the wave's 8 positions + 1.5 KB LDS
// fold; normalize+pack written straight to s_hA. hRow LDS eliminated
// (21 -> 8.2 KB); the 96-thread serial xbar loop eliminated.
// MFMA phase unchanged: B-frags from global bf16 W (L2-hot), acc[2][6].
// ---------------------------------------------------------------------------
#define TP1 32
__global__ __launch_bounds__(256, 4) void k1_rmsnorm_inproj(
    const float* __restrict__ x, const unsigned short* __restrict__ wb16,
    const float* __restrict__ norm_w,
    unsigned short* __restrict__ xs, unsigned short* __restrict__ z,
    float* __restrict__ xpart)
{
    __shared__ unsigned int s_hA[TP1 * 52];  // 6.7 KB bf16 pairs [pos][dpair]
    __shared__ float s_swap[4][96];          // 1.5 KB per-wave xbar partials

    const int tid = threadIdx.x;
    const int wave = tid >> 6, lane = tid & 63;
    const long p0 = (long)blockIdx.x * TP1;
    const int p = tid >> 3;       // 0..31 position in tile
    const int g = tid & 7;        // 0..7 element group (12 floats each)

    // load 12 elements of position p into registers (3 x float4, 16B aligned)
    const float4* xsrc = (const float4*)&x[(p0 + p) * 96 + g * 12];
    float4 xa = xsrc[0], xb = xsrc[1], xc4 = xsrc[2];

    // RMS sum-of-squares: reduce over the 8 g-lanes (contiguous in wave)
    float ss = xa.x * xa.x + xa.y * xa.y + xa.z * xa.z + xa.w * xa.w
             + xb.x * xb.x + xb.y * xb.y + xb.z * xb.z + xb.w * xb.w
             + xc4.x * xc4.x + xc4.y * xc4.y + xc4.z * xc4.z + xc4.w * xc4.w;
    ss += __shfl_xor(ss, 1);
    ss += __shfl_xor(ss, 2);
    ss += __shfl_xor(ss, 4);
    const float sc = 1.0f / sqrtf(ss * (1.0f / 96.0f) + 1e-5f);

    // xbar column partials: reduce over the wave's 8 positions (stride-8 lanes)
    {
        float c0 = xa.x, c1 = xa.y, c2 = xa.z, c3 = xa.w;
        float c4 = xb.x, c5 = xb.y, c6 = xb.z, c7 = xb.w;
        float c8 = xc4.x, c9 = xc4.y, c10 = xc4.z, c11 = xc4.w;
#pragma unroll
        for (int m = 8; m <= 32; m <<= 1) {
            c0 += __shfl_xor(c0, m);  c1 += __shfl_xor(c1, m);
            c2 += __shfl_xor(c2, m);  c3 += __shfl_xor(c3, m);
            c4 += __shfl_xor(c4, m);  c5 += __shfl_xor(c5, m);
            c6 += __shfl_xor(c6, m);  c7 += __shfl_xor(c7, m);
            c8 += __shfl_xor(c8, m);  c9 += __shfl_xor(c9, m);
            c10 += __shfl_xor(c10, m); c11 += __shfl_xor(c11, m);
        }
        if (lane < 8) {   // one lane per g-group holds the wave partial
            float* sw = &s_swap[wave][lane * 12];
            sw[0] = c0;  sw[1] = c1;  sw[2] = c2;  sw[3] = c3;
            sw[4] = c4;  sw[5] = c5;  sw[6] = c6;  sw[7] = c7;
            sw[8] = c8;  sw[9] = c9;  sw[10] = c10; sw[11] = c11;
        }
    }

    // normalize + pack straight into s_hA[p][dpair], dpairs g*6..g*6+5
    {
        const float4* nwp = (const float4*)&norm_w[g * 12];
        float4 na = nwp[0], nb = nwp[1], nc = nwp[2];
        unsigned int* dst = &s_hA[p * 52 + g * 6];
        uint2 w0, w1, w2;
        w0.x = pack_bf16(xa.x * sc * na.x, xa.y * sc * na.y);
        w0.y = pack_bf16(xa.z * sc * na.z, xa.w * sc * na.w);
        w1.x = pack_bf16(xb.x * sc * nb.x, xb.y * sc * nb.y);
        w1.y = pack_bf16(xb.z * sc * nb.z, xb.w * sc * nb.w);
        w2.x = pack_bf16(xc4.x * sc * nc.x, xc4.y * sc * nc.y);
        w2.y = pack_bf16(xc4.z * sc * nc.z, xc4.w * sc * nc.w);
        ((uint2*)dst)[0] = w0;
        ((uint2*)dst)[1] = w1;
        ((uint2*)dst)[2] = w2;
    }
    __syncthreads();   // the ONE barrier: s_hA + s_swap ready

    // xbar fold (overlaps with MFMA issue on other threads)
    if (tid < 96) {
        xpart[(long)blockIdx.x * 96 + tid] =
            s_swap[0][tid] + s_swap[1][tid] + s_swap[2][tid] + s_swap[3][tid];
    }

    const int quad = lane >> 4, ln = lane & 15;
    const int n0 = wave * 96;

    // acc[mt][nt] = D[j-tile nt][pos-tile mt] (operand-swapped mfma(W,h))
    v4f acc[2][6];
#pragma unroll
    for (int mt = 0; mt < 2; mt++)
#pragma unroll
        for (int nt = 0; nt < 6; nt++) acc[mt][nt] = (v4f){0.f, 0.f, 0.f, 0.f};

    for (int kc = 0; kc < 3; kc++) {
        v8s bfh[2];
#pragma unroll
        for (int mt = 0; mt < 2; mt++)
            bfh[mt] = *(const v8s*)&s_hA[(mt * 16 + ln) * 52 + kc * 16 + quad * 4];
#pragma unroll
        for (int nt = 0; nt < 6; nt++) {
            // B-frag straight from global bf16 W (L2-hot, 16B aligned)
            v8s aw = *(const v8s*)&wb16[(n0 + nt * 16 + ln) * 96 + kc * 32 + quad * 8];
            acc[0][nt] = __builtin_amdgcn_mfma_f32_16x16x32_bf16(aw, bfh[0], acc[0][nt], 0, 0, 0);
            acc[1][nt] = __builtin_amdgcn_mfma_f32_16x16x32_bf16(aw, bfh[1], acc[1][nt], 0, 0, 0);
        }
    }

    // epilogue: D[j][pos] — lane owns j = quad*4+r (consecutive), pos = ln.
    // z waves (2,3) apply SiLU before the bf16 pack.
    unsigned short* dst = (wave < 2) ? xs : z;
    const bool is_z = (wave >= 2);
    const int jb = (wave & 1) * 96;
#pragma unroll
    for (int mt = 0; mt < 2; mt++) {
        long pos = p0 + mt * 16 + ln;
#pragma unroll
        for (int nt = 0; nt < 6; nt++) {
            float f0 = acc[mt][nt][0], f1 = acc[mt][nt][1];
            float f2 = acc[mt][nt][2], f3 = acc[mt][nt][3];
            if (is_z) {
                f0 = silu_fast(f0); f1 = silu_fast(f1);
                f2 = silu_fast(f2); f3 = silu_fast(f3);
            }
            uint2 v;
            v.x = pack_bf16(f0, f1);
            v.y = pack_bf16(f2, f3);
            *(uint2*)&dst[pos * D_INNER + jb + nt * 16 + quad * 4] = v;
        }
    }
}

// ---------------------------------------------------------------------------
// K2F: fused conv+silu -> xc (bf16 LDS); dbc GEMM via MFMA (B-frags from the
// global bf16 x_proj_w pack); chunk scan (G-trick, power-chain exp,
// scalar-Pa). Round-18/round-5 proven form (measured 49.7 us) — the ILP-2
// half-chunk variant (round 22) was neutral-to-negative (VALUBusy 64->53)
// and is reverted.
// ---------------------------------------------------------------------------
#define SXSTR 200   // ushort stride; 100 dw, %32=4 -> bank spread; 16B-aligned
__global__ __launch_bounds__(192, 4) void k2f_conv_scan(
    const unsigned short* __restrict__ xs, const unsigned short* __restrict__ z,
    const float* __restrict__ conv_w, const float* __restrict__ conv_b,
    const unsigned short* __restrict__ xpb,
    const float* __restrict__ dt_w, const float* __restrict__ dt_b,
    const float* __restrict__ A_log, const float* __restrict__ D_param,
    float4* __restrict__ out4)
{
    __shared__ unsigned short sxc[CT2 * SXSTR];   // 12.8 KB xc tile [t][e] bf16
    __shared__ float sMeta[CT2][20];              // 2.56 KB: [0:6) dr, [8:14) Bm, [14:20) Cm
    const int e = threadIdx.x;
    const int c = blockIdx.x & (NC2 - 1);
    const int b = blockIdx.x >> 7;
    const int l0 = c * CT2;
    const long brow = (long)b * SEQLEN;

    // conv + silu -> sxc (bf16), fully unrolled rolling window
    float cw[D_CONV];
#pragma unroll
    for (int k = 0; k < D_CONV; k++) cw[k] = conv_w[e * D_CONV + k];
    const float cb = conv_b[e];
    float win[D_CONV];
#pragma unroll
    for (int k = 0; k < 8; k++) {
        int ll = l0 - 8 + k;
        win[k] = (ll >= 0) ? bf2f(xs[(brow + ll) * D_INNER + e]) : 0.0f;
    }
#pragma unroll
    for (int r = 0; r < CT2; r++) {
        win[8] = bf2f(xs[(brow + l0 + r) * D_INNER + e]);
        float s = cb;
#pragma unroll
        for (int k = 0; k < D_CONV; k++) s += win[k] * cw[k];
        sxc[r * SXSTR + e] = bf16h(silu_fast(s));
#pragma unroll
        for (int k = 0; k < 8; k++) win[k] = win[k + 1];
    }

    // prefetch z for the whole chunk (pre-silu'd; independent loads in flight)
    const unsigned short* zp = &z[(brow + l0) * D_INNER + e];
    float zv[CT2];
#pragma unroll
    for (int t = 0; t < CT2; t++) zv[t] = bf2f(zp[(long)t * D_INNER]);
    __syncthreads();

    // dbc GEMM via MFMA: D[pos][f] = sum_e xc[pos][e] * xp[f][e].
    // B fragments load directly from the packed global x_proj_w (L2-hot).
    {
        const int wave = e >> 6, lane = e & 63;
        const int quad = lane >> 4, ln = lane & 15;
        if (wave < 2) {
            const int mt = wave;
            const int r1 = (ln < 2) ? 16 + ln : 0;   // clamp: f>=18 cols discarded
            v4f dacc[2];
            dacc[0] = (v4f){0.f, 0.f, 0.f, 0.f};
            dacc[1] = (v4f){0.f, 0.f, 0.f, 0.f};
#pragma unroll
            for (int kc = 0; kc < 6; kc++) {
                v8s af  = *(const v8s*)&sxc[(mt * 16 + ln) * SXSTR + kc * 32 + quad * 8];
                v8s bf0 = *(const v8s*)&xpb[ln * 192 + kc * 32 + quad * 8];
                v8s bf1 = *(const v8s*)&xpb[r1 * 192 + kc * 32 + quad * 8];
                dacc[0] = __builtin_amdgcn_mfma_f32_16x16x32_bf16(af, bf0, dacc[0], 0, 0, 0);
                dacc[1] = __builtin_amdgcn_mfma_f32_16x16x32_bf16(af, bf1, dacc[1], 0, 0, 0);
            }
#pragma unroll
            for (int nt = 0; nt < 2; nt++) {
                int f = nt * 16 + ln;
                if (f < 18) {
                    int col = (f < 6) ? f : f + 2;
#pragma unroll
                    for (int r = 0; r < 4; r++)
                        sMeta[mt * 16 + quad * 4 + r][col] = dacc[nt][r];
                }
            }
        }
    }
    __syncthreads();

    float a[D_STATE];
#pragma unroll
    for (int n = 0; n < D_STATE; n++) a[n] = -__expf(A_log[e * D_STATE + n]);
    float dtw[DT_RANK];
#pragma unroll
    for (int q = 0; q < DT_RANK; q++) dtw[q] = dt_w[e * DT_RANK + q];
    const float dtb = dt_b[e];
    const float Dv = D_param[e];
    const float a0 = a[0];

    // structure check: a[n] == (n+1)*a0 (true for A_log = log(tile(1..6)))
    bool pok = true;
#pragma unroll
    for (int n = 1; n < D_STATE; n++)
        pok = pok && (fabsf(a[n] - (float)(n + 1) * a0)
                      <= 1e-4f * (float)(n + 1) * fabsf(a0));
    unsigned long long pmask = __ballot(pok);

    float S[D_STATE], G[D_STATE];
#pragma unroll
    for (int n = 0; n < D_STATE; n++) { S[n] = 0.0f; G[n] = 0.0f; }
    float ysum0 = 0.0f;

    if (pmask == 0xFFFFFFFFFFFFFFFFull) {
        // power-chain path: dA[n] = E^(n+1); P[n] = Pa^(n+1), Pa scalar.
        float Pa = 1.0f;
#pragma unroll 2
        for (int t = 0; t < CT2; t++) {
            const float4* m4 = (const float4*)&sMeta[t][0];
            float4 m0 = m4[0], m1 = m4[1], mB0 = m4[2], mB1 = m4[3], mC = m4[4];
            float Bv[6] = {mB0.x, mB0.y, mB0.z, mB0.w, mB1.x, mB1.y};
            float Cv[6] = {mB1.z, mB1.w, mC.x, mC.y, mC.z, mC.w};
            float dr = dtb + m0.x * dtw[0] + m0.y * dtw[1] + m0.z * dtw[2]
                     + m0.w * dtw[3] + m1.x * dtw[4] + m1.y * dtw[5];
            float dl = softplus_fast(dr);
            float xv = bf2f(sxc[t * SXSTR + e]);
            float zw = zv[t];                 // pre-silu'd
            float dx = dl * xv;
            float y = Dv * xv;
            float E = __expf(dl * a0);
            Pa *= E;
            float dA = E;
            float w = zw * Pa;               // w_n = zw * Pa^(n+1)
#pragma unroll
            for (int n = 0; n < D_STATE; n++) {
                S[n] = dA * S[n] + dx * Bv[n];
                y += S[n] * Cv[n];
                G[n] += w * Cv[n];
                dA *= E;
                w *= Pa;
            }
            ysum0 += zw * y;
        }
        long ob = (long)(b * NC2 + c) * 5 * 192 + e;
        float P1 = Pa, P2 = P1 * Pa, P3 = P2 * Pa, P4 = P3 * Pa, P5 = P4 * Pa, P6 = P5 * Pa;
        float4 q0, q1, q2, q3, q4;
        q0.x=P1; q0.y=P2; q0.z=P3; q0.w=P4;
        q1.x=P5; q1.y=P6; q1.z=S[0]; q1.w=S[1];
        q2.x=S[2]; q2.y=S[3]; q2.z=S[4]; q2.w=S[5];
        q3.x=G[0]; q3.y=G[1]; q3.z=G[2]; q3.w=G[3];
        q4.x=G[4]; q4.y=G[5]; q4.z=ysum0; q4.w=0.0f;
        out4[ob          ] = q0;
        out4[ob + 192    ] = q1;
        out4[ob + 2 * 192] = q2;
        out4[ob + 3 * 192] = q3;
        out4[ob + 4 * 192] = q4;
    } else {
        // generic path
        float P[D_STATE];
#pragma unroll
        for (int n = 0; n < D_STATE; n++) P[n] = 1.0f;
#pragma unroll 2
        for (int t = 0; t < CT2; t++) {
            const float4* m4 = (const float4*)&sMeta[t][0];
            float4 m0 = m4[0], m1 = m4[1], mB0 = m4[2], mB1 = m4[3], mC = m4[4];
            float Bv[6] = {mB0.x, mB0.y, mB0.z, mB0.w, mB1.x, mB1.y};
            float Cv[6] = {mB1.z, mB1.w, mC.x, mC.y, mC.z, mC.w};
            float dr = dtb + m0.x * dtw[0] + m0.y * dtw[1] + m0.z * dtw[2]
                     + m0.w * dtw[3] + m1.x * dtw[4] + m1.y * dtw[5];
            float dl = softplus_fast(dr);
            float xv = bf2f(sxc[t * SXSTR + e]);
            float zw = zv[t];                 // pre-silu'd
            float dx = dl * xv;
            float y = Dv * xv;
#pragma unroll
            for (int n = 0; n < D_STATE; n++) {
                float dA = __expf(dl * a[n]);
                S[n] = dA * S[n] + dx * Bv[n];
                P[n] *= dA;
                y += S[n] * Cv[n];
                G[n] += zw * P[n] * Cv[n];
            }
            ysum0 += zw * y;
        }
        long ob = (long)(b * NC2 + c) * 5 * 192 + e;
        float4 q0, q1, q2, q3, q4;
        q0.x=P[0]; q0.y=P[1]; q0.z=P[2]; q0.w=P[3];
        q1.x=P[4]; q1.y=P[5]; q1.z=S[0]; q1.w=S[1];
        q2.x=S[2]; q2.y=S[3]; q2.z=S[4]; q2.w=S[5];
        q3.x=G[0]; q3.y=G[1]; q3.z=G[2]; q3.w=G[3];
        q4.x=G[4]; q4.y=G[5]; q4.z=ysum0; q4.w=0.0f;
        out4[ob          ] = q0;
        out4[ob + 192    ] = q1;
        out4[ob + 2 * 192] = q2;
        out4[ob + 3 * 192] = q3;
        out4[ob + 4 * 192] = q4;
    }
}

// ---------------------------------------------------------------------------
// K4S: level-1 fold — compose CPS=8 chunks into one segment.
// ---------------------------------------------------------------------------
__global__ __launch_bounds__(192) void k4_seg(
    const float4* __restrict__ out4, float4* __restrict__ seg4)
{
    const int e = threadIdx.x;
    const int s = blockIdx.x & (NSEG - 1);
    const int b = blockIdx.x >> 4;

    float H[D_STATE], Gq[D_STATE], Pp[D_STATE];
#pragma unroll
    for (int n = 0; n < D_STATE; n++) { H[n] = 0.0f; Gq[n] = 0.0f; Pp[n] = 1.0f; }
    float yb = 0.0f;
#pragma unroll 2
    for (int cc = 0; cc < CPS; cc++) {
        int c = s * CPS + cc;
        long ob = (long)(b * NC2 + c) * 5 * 192 + e;
        float4 q0 = out4[ob];
        float4 q1 = out4[ob + 192];
        float4 q2 = out4[ob + 2 * 192];
        float4 q3 = out4[ob + 3 * 192];
        float4 q4 = out4[ob + 4 * 192];
        float Pv[6] = {q0.x, q0.y, q0.z, q0.w, q1.x, q1.y};
        float Sv[6] = {q1.z, q1.w, q2.x, q2.y, q2.z, q2.w};
        float Gv[6] = {q3.x, q3.y, q3.z, q3.w, q4.x, q4.y};
        float g = 0.0f;
#pragma unroll
        for (int n = 0; n < D_STATE; n++) g += Gv[n] * H[n];
        yb += q4.z + g;
#pragma unroll
        for (int n = 0; n < D_STATE; n++) {
            Gq[n] += Gv[n] * Pp[n];
            H[n] = Pv[n] * H[n] + Sv[n];
            Pp[n] *= Pv[n];
        }
    }
    long sb = (long)(b * NSEG + s) * 5 * 192 + e;
    float4 q0, q1, q2, q3, q4;
    q0.x=Pp[0]; q0.y=Pp[1]; q0.z=Pp[2]; q0.w=Pp[3];
    q1.x=Pp[4]; q1.y=Pp[5]; q1.z=H[0]; q1.w=H[1];
    q2.x=H[2]; q2.y=H[3]; q2.z=H[4]; q2.w=H[5];
    q3.x=Gq[0]; q3.y=Gq[1]; q3.z=Gq[2]; q3.w=Gq[3];
    q4.x=Gq[4]; q4.y=Gq[5]; q4.z=yb; q4.w=0.0f;
    seg4[sb          ] = q0;
    seg4[sb + 192    ] = q1;
    seg4[sb + 2 * 192] = q2;
    seg4[sb + 3 * 192] = q3;
    seg4[sb + 4 * 192] = q4;
}

// ---------------------------------------------------------------------------
// K4H: per-batch block: fold NSEG=16 segments -> ybar; fold 128 xbar
// partials (TP1=32 tiles); then output head.
// ---------------------------------------------------------------------------
__global__ __launch_bounds__(192) void k4_head(
    const float4* __restrict__ seg4, const float* __restrict__ xpart,
    const float* __restrict__ Wout,
    const float* __restrict__ fc_w, const float* __restrict__ fc_b,
    const float* __restrict__ mu_w, const float* __restrict__ mu_b,
    const float* __restrict__ sg_w, const float* __restrict__ sg_b,
    float* __restrict__ out)
{
    __shared__ float ybar[D_INNER];
    __shared__ float sxb[D_MODEL];
    __shared__ float evec[D_MODEL];
    __shared__ float feat_s[64];
    const int e = threadIdx.x;
    const int b = blockIdx.x;

    float H[D_STATE];
#pragma unroll
    for (int n = 0; n < D_STATE; n++) H[n] = 0.0f;
    float yb = 0.0f;
#pragma unroll 4
    for (int s = 0; s < NSEG; s++) {
        long ob = (long)(b * NSEG + s) * 5 * 192 + e;
        float4 q0 = seg4[ob];
        float4 q1 = seg4[ob + 192];
        float4 q2 = seg4[ob + 2 * 192];
        float4 q3 = seg4[ob + 3 * 192];
        float4 q4 = seg4[ob + 4 * 192];
        float Pv[6] = {q0.x, q0.y, q0.z, q0.w, q1.x, q1.y};
        float Sv[6] = {q1.z, q1.w, q2.x, q2.y, q2.z, q2.w};
        float Gv[6] = {q3.x, q3.y, q3.z, q3.w, q4.x, q4.y};
        float g = 0.0f;
#pragma unroll
        for (int n = 0; n < D_STATE; n++) g += Gv[n] * H[n];
        yb += q4.z + g;
#pragma unroll
        for (int n = 0; n < D_STATE; n++) H[n] = Pv[n] * H[n] + Sv[n];
    }
    ybar[e] = yb;

    // fold the 128 per-tile xbar partials for this batch (TP1=32)
    if (e < D_MODEL) {
        const float* xp = &xpart[(long)b * 128 * 96 + e];
        float s = 0.0f;
        for (int t = 0; t < 128; t++) s += xp[t * 96];
        sxb[e] = s;
    }
    __syncthreads();

    if (e < D_MODEL) {
        float s = sxb[e];
        const float* wrow = &Wout[e * D_INNER];
        for (int e2 = 0; e2 < D_INNER; e2++) s += ybar[e2] * wrow[e2];
        evec[e] = s / (float)SEQLEN;
    }
    __syncthreads();

    if (e < 64) {
        float s = fc_b[e];
        const float* wrow = &fc_w[e * D_MODEL];
        for (int d = 0; d < D_MODEL; d++) s += evec[d] * wrow[d];
        float f = eluf(tanhf(s));
        feat_s[e] = f;
        out[b * 64 + e] = f; // feat
    }
    __syncthreads();

    if (e < 64) {
        float smu = mu_b[e], ssg = sg_b[e];
        const float* mrow = &mu_w[e * 64];
        const float* srow = &sg_w[e * 64];
        for (int i = 0; i < 64; i++) {
            smu += feat_s[i] * mrow[i];
            ssg += feat_s[i] * srow[i];
        }
        out[1024 + b * 64 + e] = smu;                        // mu
        out[2048 + b * 64 + e] = eluf(ssg) + 1.0f + 1e-14f;  // sigma
    }
}

extern "C" void kernel_launch(void* const* d_in, const int* in_sizes, int n_in,
                              void* d_out, int out_size, void* d_ws, size_t ws_size,
                              hipStream_t stream) {
    const float* x         = (const float*)d_in[0];
    const float* in_proj_w = (const float*)d_in[1];
    const float* conv_w    = (const float*)d_in[2];
    const float* conv_b    = (const float*)d_in[3];
    const float* x_proj_w  = (const float*)d_in[4];
    const float* dt_proj_w = (const float*)d_in[5];
    const float* dt_proj_b = (const float*)d_in[6];
    const float* A_log     = (const float*)d_in[7];
    const float* D_param   = (const float*)d_in[8];
    const float* out_proj_w= (const float*)d_in[9];
    const float* norm_w    = (const float*)d_in[10];
    const float* out_fc_w  = (const float*)d_in[11];
    const float* out_fc_b  = (const float*)d_in[12];
    const float* mu_w      = (const float*)d_in[13];
    const float* mu_b      = (const float*)d_in[14];
    const float* sigma_w   = (const float*)d_in[15];
    const float* sigma_b   = (const float*)d_in[16];
    float* ws = (float*)d_ws;
    float* out = (float*)d_out;

    k0_pack<<<(K0_W + K0_X + 255) / 256, 256, 0, stream>>>(
        in_proj_w, x_proj_w,
        (unsigned int*)(ws + OFF_WB16), (unsigned int*)(ws + OFF_XPB));

    k1_rmsnorm_inproj<<<NPOS / TP1, 256, 0, stream>>>(
        x, (const unsigned short*)(ws + OFF_WB16), norm_w,
        (unsigned short*)(ws + OFF_XS), (unsigned short*)(ws + OFF_Z),
        ws + OFF_XPART);

    k2f_conv_scan<<<BATCH * NC2, 192, 0, stream>>>(
        (const unsigned short*)(ws + OFF_XS), (const unsigned short*)(ws + OFF_Z),
        conv_w, conv_b, (const unsigned short*)(ws + OFF_XPB),
        dt_proj_w, dt_proj_b, A_log, D_param,
        (float4*)(ws + OFF_OUT4));

    k4_seg<<<BATCH * NSEG, 192, 0, stream>>>(
        (const float4*)(ws + OFF_OUT4), (float4*)(ws + OFF_SEG));

    k4_head<<<BATCH, 192, 0, stream>>>(
        (const float4*)(ws + OFF_SEG), ws + OFF_XPART, out_proj_w,
        out_fc_w, out_fc_b, mu_w, mu_b, sigma_w, sigma_b, out);
}

// Round 9
// 189.784 us; speedup vs baseline: 1.0922x; 1.0088x over previous
//
#include <hip/hip_runtime.h>
#include <math.h>

#define BATCH 16
#define SEQLEN 4096
#define D_MODEL 96
#define D_STATE 6
#define D_CONV 9
#define D_INNER 192
#define DT_RANK 6
#define NPOS (BATCH * SEQLEN)

#define NC2 128            // chunks per sequence
#define CT2 (SEQLEN / NC2) // 32 steps per chunk
#define NSEG 16            // level-2 segments
#define CPS (NC2 / NSEG)   // chunks per segment = 8

// workspace layout (in floats). xs/z stored as bf16 (ushort). z is PRE-SILU'd.
#define OFF_XS    0L
#define OFF_Z     (OFF_XS   + (long)NPOS * 96)
#define OFF_OUT4  (OFF_Z    + (long)NPOS * 96)       // B*NC2*5*192 float4s
#define OFF_SEG   (OFF_OUT4 + (long)BATCH * NC2 * 5 * 192 * 4)
#define OFF_XPART (OFF_SEG  + (long)BATCH * NSEG * 5 * 192 * 4)  // 2048*96 xbar partials
#define OFF_XPB   (OFF_XPART + (long)(NPOS / 32) * 96)           // 18x192 bf16 x_proj_w
#define OFF_WB16  (OFF_XPB  + 18 * 96)                           // 384x96 bf16 in_proj_w

typedef short v8s __attribute__((ext_vector_type(8)));   // 8 x bf16 (MFMA A/B frag)
typedef float v4f __attribute__((ext_vector_type(4)));   // MFMA C/D frag

// fast transcendentals — abs threshold 2e-2, ample headroom
__device__ __forceinline__ float silu_fast(float v) {
    return __fdividef(v, 1.0f + __expf(-v));
}
__device__ __forceinline__ float softplus_fast(float v) {
    return (v > 20.0f) ? v : __logf(1.0f + __expf(v));
}
__device__ __forceinline__ float eluf(float v) {
    return (v > 0.0f) ? v : expm1f(v);
}
__device__ __forceinline__ unsigned int pack_bf16(float a, float b) {
    unsigned int ua = __float_as_uint(a), ub = __float_as_uint(b);
    ua += 0x7FFFu + ((ua >> 16) & 1u);
    ub += 0x7FFFu + ((ub >> 16) & 1u);
    return (ua >> 16) | (ub & 0xFFFF0000u);
}
__device__ __forceinline__ unsigned short bf16h(float v) {
    unsigned int u = __float_as_uint(v);
    u += 0x7FFFu + ((u >> 16) & 1u);
    return (unsigned short)(u >> 16);
}
__device__ __forceinline__ float bf2f(unsigned short h) {
    return __uint_as_float(((unsigned int)h) << 16);
}

// ---------------------------------------------------------------------------
// K0: one-time weight packs (f32 -> bf16): in_proj_w (384x96) and
// x_proj_w (18x192).
// ---------------------------------------------------------------------------
#define K0_W (384 * 48)
#define K0_X (18 * 96)
__global__ __launch_bounds__(256) void k0_pack(
    const float* __restrict__ W, const float* __restrict__ x_proj_w,
    unsigned int* __restrict__ wb16, unsigned int* __restrict__ xpb)
{
    int i = blockIdx.x * 256 + threadIdx.x;
    if (i < K0_W) {
        const float2 wv = *(const float2*)&W[2 * i];
        wb16[i] = pack_bf16(wv.x, wv.y);
    } else if (i < K0_W + K0_X) {
        int j = i - K0_W;
        const float2 wv = *(const float2*)&x_proj_w[2 * j];
        xpb[j] = pack_bf16(wv.x, wv.y);
    }
}

// ---------------------------------------------------------------------------
// K1 (MFMA): RMSNorm + in_proj via bf16 mfma_f32_16x16x32.
// Round 24: software-pipelined W loads. kc=0's 6 B-fragments are issued
// BEFORE the prologue (latency hides under RMS/pack); each kc's MFMA
// overlaps kc+1's loads via explicit ping-pong (aw0/aw1, static indexing).
// Round-23 register prologue retained: one barrier, 8.2 KB LDS.
// ---------------------------------------------------------------------------
#define TP1 32
__global__ __launch_bounds__(256, 4) void k1_rmsnorm_inproj(
    const float* __restrict__ x, const unsigned short* __restrict__ wb16,
    const float* __restrict__ norm_w,
    unsigned short* __restrict__ xs, unsigned short* __restrict__ z,
    float* __restrict__ xpart)
{
    __shared__ unsigned int s_hA[TP1 * 52];  // 6.7 KB bf16 pairs [pos][dpair]
    __shared__ float s_swap[4][96];          // 1.5 KB per-wave xbar partials

    const int tid = threadIdx.x;
    const int wave = tid >> 6, lane = tid & 63;
    const int quad = lane >> 4, ln = lane & 15;
    const int n0 = wave * 96;
    const long p0 = (long)blockIdx.x * TP1;
    const int p = tid >> 3;       // 0..31 position in tile
    const int g = tid & 7;        // 0..7 element group (12 floats each)

    // issue kc=0 W-fragment loads NOW — latency hidden under the prologue
    const unsigned short* wrow = &wb16[(n0 + ln) * 96 + quad * 8];
    v8s aw0[6], aw1[6];
#pragma unroll
    for (int nt = 0; nt < 6; nt++)
        aw0[nt] = *(const v8s*)&wrow[nt * 16 * 96];

    // load 12 elements of position p into registers (3 x float4, 16B aligned)
    const float4* xsrc = (const float4*)&x[(p0 + p) * 96 + g * 12];
    float4 xa = xsrc[0], xb = xsrc[1], xc4 = xsrc[2];

    // RMS sum-of-squares: reduce over the 8 g-lanes (contiguous in wave)
    float ss = xa.x * xa.x + xa.y * xa.y + xa.z * xa.z + xa.w * xa.w
             + xb.x * xb.x + xb.y * xb.y + xb.z * xb.z + xb.w * xb.w
             + xc4.x * xc4.x + xc4.y * xc4.y + xc4.z * xc4.z + xc4.w * xc4.w;
    ss += __shfl_xor(ss, 1);
    ss += __shfl_xor(ss, 2);
    ss += __shfl_xor(ss, 4);
    const float sc = 1.0f / sqrtf(ss * (1.0f / 96.0f) + 1e-5f);

    // xbar column partials: reduce over the wave's 8 positions (stride-8 lanes)
    {
        float c0 = xa.x, c1 = xa.y, c2 = xa.z, c3 = xa.w;
        float c4 = xb.x, c5 = xb.y, c6 = xb.z, c7 = xb.w;
        float c8 = xc4.x, c9 = xc4.y, c10 = xc4.z, c11 = xc4.w;
#pragma unroll
        for (int m = 8; m <= 32; m <<= 1) {
            c0 += __shfl_xor(c0, m);  c1 += __shfl_xor(c1, m);
            c2 += __shfl_xor(c2, m);  c3 += __shfl_xor(c3, m);
            c4 += __shfl_xor(c4, m);  c5 += __shfl_xor(c5, m);
            c6 += __shfl_xor(c6, m);  c7 += __shfl_xor(c7, m);
            c8 += __shfl_xor(c8, m);  c9 += __shfl_xor(c9, m);
            c10 += __shfl_xor(c10, m); c11 += __shfl_xor(c11, m);
        }
        if (lane < 8) {   // one lane per g-group holds the wave partial
            float* sw = &s_swap[wave][lane * 12];
            sw[0] = c0;  sw[1] = c1;  sw[2] = c2;  sw[3] = c3;
            sw[4] = c4;  sw[5] = c5;  sw[6] = c6;  sw[7] = c7;
            sw[8] = c8;  sw[9] = c9;  sw[10] = c10; sw[11] = c11;
        }
    }

    // normalize + pack straight into s_hA[p][dpair], dpairs g*6..g*6+5
    {
        const float4* nwp = (const float4*)&norm_w[g * 12];
        float4 na = nwp[0], nb = nwp[1], nc = nwp[2];
        unsigned int* dst = &s_hA[p * 52 + g * 6];
        uint2 w0, w1, w2;
        w0.x = pack_bf16(xa.x * sc * na.x, xa.y * sc * na.y);
        w0.y = pack_bf16(xa.z * sc * na.z, xa.w * sc * na.w);
        w1.x = pack_bf16(xb.x * sc * nb.x, xb.y * sc * nb.y);
        w1.y = pack_bf16(xb.z * sc * nb.z, xb.w * sc * nb.w);
        w2.x = pack_bf16(xc4.x * sc * nc.x, xc4.y * sc * nc.y);
        w2.y = pack_bf16(xc4.z * sc * nc.z, xc4.w * sc * nc.w);
        ((uint2*)dst)[0] = w0;
        ((uint2*)dst)[1] = w1;
        ((uint2*)dst)[2] = w2;
    }
    __syncthreads();   // the ONE barrier: s_hA + s_swap ready

    // xbar fold (overlaps with MFMA issue on other threads)
    if (tid < 96) {
        xpart[(long)blockIdx.x * 96 + tid] =
            s_swap[0][tid] + s_swap[1][tid] + s_swap[2][tid] + s_swap[3][tid];
    }

    // acc[mt][nt] = D[j-tile nt][pos-tile mt] (operand-swapped mfma(W,h))
    v4f acc[2][6];
#pragma unroll
    for (int mt = 0; mt < 2; mt++)
#pragma unroll
        for (int nt = 0; nt < 6; nt++) acc[mt][nt] = (v4f){0.f, 0.f, 0.f, 0.f};

    // ---- kc = 0: prefetch kc=1, MFMA with aw0 ----
#pragma unroll
    for (int nt = 0; nt < 6; nt++)
        aw1[nt] = *(const v8s*)&wrow[nt * 16 * 96 + 1 * 32];
    {
        v8s bfh0 = *(const v8s*)&s_hA[(0 * 16 + ln) * 52 + 0 * 16 + quad * 4];
        v8s bfh1 = *(const v8s*)&s_hA[(1 * 16 + ln) * 52 + 0 * 16 + quad * 4];
#pragma unroll
        for (int nt = 0; nt < 6; nt++) {
            acc[0][nt] = __builtin_amdgcn_mfma_f32_16x16x32_bf16(aw0[nt], bfh0, acc[0][nt], 0, 0, 0);
            acc[1][nt] = __builtin_amdgcn_mfma_f32_16x16x32_bf16(aw0[nt], bfh1, acc[1][nt], 0, 0, 0);
        }
    }
    // ---- kc = 1: prefetch kc=2 into aw0, MFMA with aw1 ----
#pragma unroll
    for (int nt = 0; nt < 6; nt++)
        aw0[nt] = *(const v8s*)&wrow[nt * 16 * 96 + 2 * 32];
    {
        v8s bfh0 = *(const v8s*)&s_hA[(0 * 16 + ln) * 52 + 1 * 16 + quad * 4];
        v8s bfh1 = *(const v8s*)&s_hA[(1 * 16 + ln) * 52 + 1 * 16 + quad * 4];
#pragma unroll
        for (int nt = 0; nt < 6; nt++) {
            acc[0][nt] = __builtin_amdgcn_mfma_f32_16x16x32_bf16(aw1[nt], bfh0, acc[0][nt], 0, 0, 0);
            acc[1][nt] = __builtin_amdgcn_mfma_f32_16x16x32_bf16(aw1[nt], bfh1, acc[1][nt], 0, 0, 0);
        }
    }
    // ---- kc = 2: MFMA with aw0 ----
    {
        v8s bfh0 = *(const v8s*)&s_hA[(0 * 16 + ln) * 52 + 2 * 16 + quad * 4];
        v8s bfh1 = *(const v8s*)&s_hA[(1 * 16 + ln) * 52 + 2 * 16 + quad * 4];
#pragma unroll
        for (int nt = 0; nt < 6; nt++) {
            acc[0][nt] = __builtin_amdgcn_mfma_f32_16x16x32_bf16(aw0[nt], bfh0, acc[0][nt], 0, 0, 0);
            acc[1][nt] = __builtin_amdgcn_mfma_f32_16x16x32_bf16(aw0[nt], bfh1, acc[1][nt], 0, 0, 0);
        }
    }

    // epilogue: D[j][pos] — lane owns j = quad*4+r (consecutive), pos = ln.
    // z waves (2,3) apply SiLU before the bf16 pack.
    unsigned short* dst = (wave < 2) ? xs : z;
    const bool is_z = (wave >= 2);
    const int jb = (wave & 1) * 96;
#pragma unroll
    for (int mt = 0; mt < 2; mt++) {
        long pos = p0 + mt * 16 + ln;
#pragma unroll
        for (int nt = 0; nt < 6; nt++) {
            float f0 = acc[mt][nt][0], f1 = acc[mt][nt][1];
            float f2 = acc[mt][nt][2], f3 = acc[mt][nt][3];
            if (is_z) {
                f0 = silu_fast(f0); f1 = silu_fast(f1);
                f2 = silu_fast(f2); f3 = silu_fast(f3);
            }
            uint2 v;
            v.x = pack_bf16(f0, f1);
            v.y = pack_bf16(f2, f3);
            *(uint2*)&dst[pos * D_INNER + jb + nt * 16 + quad * 4] = v;
        }
    }
}

// ---------------------------------------------------------------------------
// K2F: fused conv+silu -> xc (bf16 LDS); dbc GEMM via MFMA (B-frags from the
// global bf16 x_proj_w pack); chunk scan (G-trick, power-chain exp,
// scalar-Pa). Proven round-18 form (49.5 us) — FROZEN.
// ---------------------------------------------------------------------------
#define SXSTR 200   // ushort stride; 100 dw, %32=4 -> bank spread; 16B-aligned
__global__ __launch_bounds__(192, 4) void k2f_conv_scan(
    const unsigned short* __restrict__ xs, const unsigned short* __restrict__ z,
    const float* __restrict__ conv_w, const float* __restrict__ conv_b,
    const unsigned short* __restrict__ xpb,
    const float* __restrict__ dt_w, const float* __restrict__ dt_b,
    const float* __restrict__ A_log, const float* __restrict__ D_param,
    float4* __restrict__ out4)
{
    __shared__ unsigned short sxc[CT2 * SXSTR];   // 12.8 KB xc tile [t][e] bf16
    __shared__ float sMeta[CT2][20];              // 2.56 KB: [0:6) dr, [8:14) Bm, [14:20) Cm
    const int e = threadIdx.x;
    const int c = blockIdx.x & (NC2 - 1);
    const int b = blockIdx.x >> 7;
    const int l0 = c * CT2;
    const long brow = (long)b * SEQLEN;

    // conv + silu -> sxc (bf16), fully unrolled rolling window
    float cw[D_CONV];
#pragma unroll
    for (int k = 0; k < D_CONV; k++) cw[k] = conv_w[e * D_CONV + k];
    const float cb = conv_b[e];
    float win[D_CONV];
#pragma unroll
    for (int k = 0; k < 8; k++) {
        int ll = l0 - 8 + k;
        win[k] = (ll >= 0) ? bf2f(xs[(brow + ll) * D_INNER + e]) : 0.0f;
    }
#pragma unroll
    for (int r = 0; r < CT2; r++) {
        win[8] = bf2f(xs[(brow + l0 + r) * D_INNER + e]);
        float s = cb;
#pragma unroll
        for (int k = 0; k < D_CONV; k++) s += win[k] * cw[k];
        sxc[r * SXSTR + e] = bf16h(silu_fast(s));
#pragma unroll
        for (int k = 0; k < 8; k++) win[k] = win[k + 1];
    }

    // prefetch z for the whole chunk (pre-silu'd; independent loads in flight)
    const unsigned short* zp = &z[(brow + l0) * D_INNER + e];
    float zv[CT2];
#pragma unroll
    for (int t = 0; t < CT2; t++) zv[t] = bf2f(zp[(long)t * D_INNER]);
    __syncthreads();

    // dbc GEMM via MFMA: D[pos][f] = sum_e xc[pos][e] * xp[f][e].
    // B fragments load directly from the packed global x_proj_w (L2-hot).
    {
        const int wave = e >> 6, lane = e & 63;
        const int quad = lane >> 4, ln = lane & 15;
        if (wave < 2) {
            const int mt = wave;
            const int r1 = (ln < 2) ? 16 + ln : 0;   // clamp: f>=18 cols discarded
            v4f dacc[2];
            dacc[0] = (v4f){0.f, 0.f, 0.f, 0.f};
            dacc[1] = (v4f){0.f, 0.f, 0.f, 0.f};
#pragma unroll
            for (int kc = 0; kc < 6; kc++) {
                v8s af  = *(const v8s*)&sxc[(mt * 16 + ln) * SXSTR + kc * 32 + quad * 8];
                v8s bf0 = *(const v8s*)&xpb[ln * 192 + kc * 32 + quad * 8];
                v8s bf1 = *(const v8s*)&xpb[r1 * 192 + kc * 32 + quad * 8];
                dacc[0] = __builtin_amdgcn_mfma_f32_16x16x32_bf16(af, bf0, dacc[0], 0, 0, 0);
                dacc[1] = __builtin_amdgcn_mfma_f32_16x16x32_bf16(af, bf1, dacc[1], 0, 0, 0);
            }
#pragma unroll
            for (int nt = 0; nt < 2; nt++) {
                int f = nt * 16 + ln;
                if (f < 18) {
                    int col = (f < 6) ? f : f + 2;
#pragma unroll
                    for (int r = 0; r < 4; r++)
                        sMeta[mt * 16 + quad * 4 + r][col] = dacc[nt][r];
                }
            }
        }
    }
    __syncthreads();

    float a[D_STATE];
#pragma unroll
    for (int n = 0; n < D_STATE; n++) a[n] = -__expf(A_log[e * D_STATE + n]);
    float dtw[DT_RANK];
#pragma unroll
    for (int q = 0; q < DT_RANK; q++) dtw[q] = dt_w[e * DT_RANK + q];
    const float dtb = dt_b[e];
    const float Dv = D_param[e];
    const float a0 = a[0];

    // structure check: a[n] == (n+1)*a0 (true for A_log = log(tile(1..6)))
    bool pok = true;
#pragma unroll
    for (int n = 1; n < D_STATE; n++)
        pok = pok && (fabsf(a[n] - (float)(n + 1) * a0)
                      <= 1e-4f * (float)(n + 1) * fabsf(a0));
    unsigned long long pmask = __ballot(pok);

    float S[D_STATE], G[D_STATE];
#pragma unroll
    for (int n = 0; n < D_STATE; n++) { S[n] = 0.0f; G[n] = 0.0f; }
    float ysum0 = 0.0f;

    if (pmask == 0xFFFFFFFFFFFFFFFFull) {
        // power-chain path: dA[n] = E^(n+1); P[n] = Pa^(n+1), Pa scalar.
        float Pa = 1.0f;
#pragma unroll 2
        for (int t = 0; t < CT2; t++) {
            const float4* m4 = (const float4*)&sMeta[t][0];
            float4 m0 = m4[0], m1 = m4[1], mB0 = m4[2], mB1 = m4[3], mC = m4[4];
            float Bv[6] = {mB0.x, mB0.y, mB0.z, mB0.w, mB1.x, mB1.y};
            float Cv[6] = {mB1.z, mB1.w, mC.x, mC.y, mC.z, mC.w};
            float dr = dtb + m0.x * dtw[0] + m0.y * dtw[1] + m0.z * dtw[2]
                     + m0.w * dtw[3] + m1.x * dtw[4] + m1.y * dtw[5];
            float dl = softplus_fast(dr);
            float xv = bf2f(sxc[t * SXSTR + e]);
            float zw = zv[t];                 // pre-silu'd
            float dx = dl * xv;
            float y = Dv * xv;
            float E = __expf(dl * a0);
            Pa *= E;
            float dA = E;
            float w = zw * Pa;               // w_n = zw * Pa^(n+1)
#pragma unroll
            for (int n = 0; n < D_STATE; n++) {
                S[n] = dA * S[n] + dx * Bv[n];
                y += S[n] * Cv[n];
                G[n] += w * Cv[n];
                dA *= E;
                w *= Pa;
            }
            ysum0 += zw * y;
        }
        long ob = (long)(b * NC2 + c) * 5 * 192 + e;
        float P1 = Pa, P2 = P1 * Pa, P3 = P2 * Pa, P4 = P3 * Pa, P5 = P4 * Pa, P6 = P5 * Pa;
        float4 q0, q1, q2, q3, q4;
        q0.x=P1; q0.y=P2; q0.z=P3; q0.w=P4;
        q1.x=P5; q1.y=P6; q1.z=S[0]; q1.w=S[1];
        q2.x=S[2]; q2.y=S[3]; q2.z=S[4]; q2.w=S[5];
        q3.x=G[0]; q3.y=G[1]; q3.z=G[2]; q3.w=G[3];
        q4.x=G[4]; q4.y=G[5]; q4.z=ysum0; q4.w=0.0f;
        out4[ob          ] = q0;
        out4[ob + 192    ] = q1;
        out4[ob + 2 * 192] = q2;
        out4[ob + 3 * 192] = q3;
        out4[ob + 4 * 192] = q4;
    } else {
        // generic path
        float P[D_STATE];
#pragma unroll
        for (int n = 0; n < D_STATE; n++) P[n] = 1.0f;
#pragma unroll 2
        for (int t = 0; t < CT2; t++) {
            const float4* m4 = (const float4*)&sMeta[t][0];
            float4 m0 = m4[0], m1 = m4[1], mB0 = m4[2], mB1 = m4[3], mC = m4[4];
            float Bv[6] = {mB0.x, mB0.y, mB0.z, mB0.w, mB1.x, mB1.y};
            float Cv[6] = {mB1.z, mB1.w, mC.x, mC.y, mC.z, mC.w};
            float dr = dtb + m0.x * dtw[0] + m0.y * dtw[1] + m0.z * dtw[2]
                     + m0.w * dtw[3] + m1.x * dtw[4] + m1.y * dtw[5];
            float dl = softplus_fast(dr);
            float xv = bf2f(sxc[t * SXSTR + e]);
            float zw = zv[t];                 // pre-silu'd
            float dx = dl * xv;
            float y = Dv * xv;
#pragma unroll
            for (int n = 0; n < D_STATE; n++) {
                float dA = __expf(dl * a[n]);
                S[n] = dA * S[n] + dx * Bv[n];
                P[n] *= dA;
                y += S[n] * Cv[n];
                G[n] += zw * P[n] * Cv[n];
            }
            ysum0 += zw * y;
        }
        long ob = (long)(b * NC2 + c) * 5 * 192 + e;
        float4 q0, q1, q2, q3, q4;
        q0.x=P[0]; q0.y=P[1]; q0.z=P[2]; q0.w=P[3];
        q1.x=P[4]; q1.y=P[5]; q1.z=S[0]; q1.w=S[1];
        q2.x=S[2]; q2.y=S[3]; q2.z=S[4]; q2.w=S[5];
        q3.x=G[0]; q3.y=G[1]; q3.z=G[2]; q3.w=G[3];
        q4.x=G[4]; q4.y=G[5]; q4.z=ysum0; q4.w=0.0f;
        out4[ob          ] = q0;
        out4[ob + 192    ] = q1;
        out4[ob + 2 * 192] = q2;
        out4[ob + 3 * 192] = q3;
        out4[ob + 4 * 192] = q4;
    }
}

// ---------------------------------------------------------------------------
// K4S: level-1 fold — compose CPS=8 chunks into one segment.
// ---------------------------------------------------------------------------
__global__ __launch_bounds__(192) void k4_seg(
    const float4* __restrict__ out4, float4* __restrict__ seg4)
{
    const int e = threadIdx.x;
    const int s = blockIdx.x & (NSEG - 1);
    const int b = blockIdx.x >> 4;

    float H[D_STATE], Gq[D_STATE], Pp[D_STATE];
#pragma unroll
    for (int n = 0; n < D_STATE; n++) { H[n] = 0.0f; Gq[n] = 0.0f; Pp[n] = 1.0f; }
    float yb = 0.0f;
#pragma unroll 2
    for (int cc = 0; cc < CPS; cc++) {
        int c = s * CPS + cc;
        long ob = (long)(b * NC2 + c) * 5 * 192 + e;
        float4 q0 = out4[ob];
        float4 q1 = out4[ob + 192];
        float4 q2 = out4[ob + 2 * 192];
        float4 q3 = out4[ob + 3 * 192];
        float4 q4 = out4[ob + 4 * 192];
        float Pv[6] = {q0.x, q0.y, q0.z, q0.w, q1.x, q1.y};
        float Sv[6] = {q1.z, q1.w, q2.x, q2.y, q2.z, q2.w};
        float Gv[6] = {q3.x, q3.y, q3.z, q3.w, q4.x, q4.y};
        float g = 0.0f;
#pragma unroll
        for (int n = 0; n < D_STATE; n++) g += Gv[n] * H[n];
        yb += q4.z + g;
#pragma unroll
        for (int n = 0; n < D_STATE; n++) {
            Gq[n] += Gv[n] * Pp[n];
            H[n] = Pv[n] * H[n] + Sv[n];
            Pp[n] *= Pv[n];
        }
    }
    long sb = (long)(b * NSEG + s) * 5 * 192 + e;
    float4 q0, q1, q2, q3, q4;
    q0.x=Pp[0]; q0.y=Pp[1]; q0.z=Pp[2]; q0.w=Pp[3];
    q1.x=Pp[4]; q1.y=Pp[5]; q1.z=H[0]; q1.w=H[1];
    q2.x=H[2]; q2.y=H[3]; q2.z=H[4]; q2.w=H[5];
    q3.x=Gq[0]; q3.y=Gq[1]; q3.z=Gq[2]; q3.w=Gq[3];
    q4.x=Gq[4]; q4.y=Gq[5]; q4.z=yb; q4.w=0.0f;
    seg4[sb          ] = q0;
    seg4[sb + 192    ] = q1;
    seg4[sb + 2 * 192] = q2;
    seg4[sb + 3 * 192] = q3;
    seg4[sb + 4 * 192] = q4;
}

// ---------------------------------------------------------------------------
// K4H: per-batch block: fold NSEG=16 segments -> ybar; fold 128 xbar
// partials (TP1=32 tiles); then output head.
// ---------------------------------------------------------------------------
__global__ __launch_bounds__(192) void k4_head(
    const float4* __restrict__ seg4, const float* __restrict__ xpart,
    const float* __restrict__ Wout,
    const float* __restrict__ fc_w, const float* __restrict__ fc_b,
    const float* __restrict__ mu_w, const float* __restrict__ mu_b,
    const float* __restrict__ sg_w, const float* __restrict__ sg_b,
    float* __restrict__ out)
{
    __shared__ float ybar[D_INNER];
    __shared__ float sxb[D_MODEL];
    __shared__ float evec[D_MODEL];
    __shared__ float feat_s[64];
    const int e = threadIdx.x;
    const int b = blockIdx.x;

    float H[D_STATE];
#pragma unroll
    for (int n = 0; n < D_STATE; n++) H[n] = 0.0f;
    float yb = 0.0f;
#pragma unroll 4
    for (int s = 0; s < NSEG; s++) {
        long ob = (long)(b * NSEG + s) * 5 * 192 + e;
        float4 q0 = seg4[ob];
        float4 q1 = seg4[ob + 192];
        float4 q2 = seg4[ob + 2 * 192];
        float4 q3 = seg4[ob + 3 * 192];
        float4 q4 = seg4[ob + 4 * 192];
        float Pv[6] = {q0.x, q0.y, q0.z, q0.w, q1.x, q1.y};
        float Sv[6] = {q1.z, q1.w, q2.x, q2.y, q2.z, q2.w};
        float Gv[6] = {q3.x, q3.y, q3.z, q3.w, q4.x, q4.y};
        float g = 0.0f;
#pragma unroll
        for (int n = 0; n < D_STATE; n++) g += Gv[n] * H[n];
        yb += q4.z + g;
#pragma unroll
        for (int n = 0; n < D_STATE; n++) H[n] = Pv[n] * H[n] + Sv[n];
    }
    ybar[e] = yb;

    // fold the 128 per-tile xbar partials for this batch (TP1=32)
    if (e < D_MODEL) {
        const float* xp = &xpart[(long)b * 128 * 96 + e];
        float s = 0.0f;
        for (int t = 0; t < 128; t++) s += xp[t * 96];
        sxb[e] = s;
    }
    __syncthreads();

    if (e < D_MODEL) {
        float s = sxb[e];
        const float* wrow = &Wout[e * D_INNER];
        for (int e2 = 0; e2 < D_INNER; e2++) s += ybar[e2] * wrow[e2];
        evec[e] = s / (float)SEQLEN;
    }
    __syncthreads();

    if (e < 64) {
        float s = fc_b[e];
        const float* wrow = &fc_w[e * D_MODEL];
        for (int d = 0; d < D_MODEL; d++) s += evec[d] * wrow[d];
        float f = eluf(tanhf(s));
        feat_s[e] = f;
        out[b * 64 + e] = f; // feat
    }
    __syncthreads();

    if (e < 64) {
        float smu = mu_b[e], ssg = sg_b[e];
        const float* mrow = &mu_w[e * 64];
        const float* srow = &sg_w[e * 64];
        for (int i = 0; i < 64; i++) {
            smu += feat_s[i] * mrow[i];
            ssg += feat_s[i] * srow[i];
        }
        out[1024 + b * 64 + e] = smu;                        // mu
        out[2048 + b * 64 + e] = eluf(ssg) + 1.0f + 1e-14f;  // sigma
    }
}

extern "C" void kernel_launch(void* const* d_in, const int* in_sizes, int n_in,
                              void* d_out, int out_size, void* d_ws, size_t ws_size,
                              hipStream_t stream) {
    const float* x         = (const float*)d_in[0];
    const float* in_proj_w = (const float*)d_in[1];
    const float* conv_w    = (const float*)d_in[2];
    const float* conv_b    = (const float*)d_in[3];
    const float* x_proj_w  = (const float*)d_in[4];
    const float* dt_proj_w = (const float*)d_in[5];
    const float* dt_proj_b = (const float*)d_in[6];
    const float* A_log     = (const float*)d_in[7];
    const float* D_param   = (const float*)d_in[8];
    const float* out_proj_w= (const float*)d_in[9];
    const float* norm_w    = (const float*)d_in[10];
    const float* out_fc_w  = (const float*)d_in[11];
    const float* out_fc_b  = (const float*)d_in[12];
    const float* mu_w      = (const float*)d_in[13];
    const float* mu_b      = (const float*)d_in[14];
    const float* sigma_w   = (const float*)d_in[15];
    const float* sigma_b   = (const float*)d_in[16];
    float* ws = (float*)d_ws;
    float* out = (float*)d_out;

    k0_pack<<<(K0_W + K0_X + 255) / 256, 256, 0, stream>>>(
        in_proj_w, x_proj_w,
        (unsigned int*)(ws + OFF_WB16), (unsigned int*)(ws + OFF_XPB));

    k1_rmsnorm_inproj<<<NPOS / TP1, 256, 0, stream>>>(
        x, (const unsigned short*)(ws + OFF_WB16), norm_w,
        (unsigned short*)(ws + OFF_XS), (unsigned short*)(ws + OFF_Z),
        ws + OFF_XPART);

    k2f_conv_scan<<<BATCH * NC2, 192, 0, stream>>>(
        (const unsigned short*)(ws + OFF_XS), (const unsigned short*)(ws + OFF_Z),
        conv_w, conv_b, (const unsigned short*)(ws + OFF_XPB),
        dt_proj_w, dt_proj_b, A_log, D_param,
        (float4*)(ws + OFF_OUT4));

    k4_seg<<<BATCH * NSEG, 192, 0, stream>>>(
        (const float4*)(ws + OFF_OUT4), (float4*)(ws + OFF_SEG));

    k4_head<<<BATCH, 192, 0, stream>>>(
        (const float4*)(ws + OFF_SEG), ws + OFF_XPART, out_proj_w,
        out_fc_w, out_fc_b, mu_w, mu_b, sigma_w, sigma_b, out);
}